// Round 10
// baseline (364.354 us; speedup 1.0000x reference)
//
#include <hip/hip_runtime.h>
#include <hip/hip_bf16.h>
#include <hip/hip_fp16.h>
#include <math.h>

#define N_HEADN 100000
#define N_TAILN 100000
#define NEDGE   1600000
#define SLOPE   0.2f

#define NB   196      // buckets: head>>9
#define HPB  512      // heads per bucket
#define BCAP 9216     // bucket capacity (mean 8191, sigma ~90; 9216 = +11 sigma)

static __device__ __forceinline__ float bf2f(__hip_bfloat16 x) { return __bfloat162float(x); }

// f16 source (lo/hi half of packed u32), fp32 multiplier + fp32 accumulate, 1 instr/dim
#define FMA_MIX_LO(acc, pk, q) \
  asm("v_fma_mix_f32 %0, %1, %2, %0 op_sel_hi:[1,0,0]" : "+v"(acc) : "v"(pk), "v"(q))
#define FMA_MIX_HI(acc, pk, q) \
  asm("v_fma_mix_f32 %0, %1, %2, %0 op_sel:[1,0,0] op_sel_hi:[1,0,0]" : "+v"(acc) : "v"(pk), "v"(q))

// ---------------- k0m: merged { W->bf16 conversion } + { wl[128][4], he[8][4] prep } ----
__global__ __launch_bounds__(256) void k0m(const float* __restrict__ W,
                                           const float* __restrict__ W_e,
                                           const float* __restrict__ a_l,
                                           const float* __restrict__ a_e,
                                           const float* __restrict__ emb,
                                           __hip_bfloat16* __restrict__ Wb,
                                           float* __restrict__ wl,
                                           float* __restrict__ he) {
  const int i = (blockIdx.x * 256 + threadIdx.x) * 4;
  const float4 v = *(const float4*)&W[i];
  union { unsigned short us[4]; uint2 u2; } pk;
  __hip_bfloat16 b0 = __float2bfloat16(v.x); pk.us[0] = *(unsigned short*)&b0;
  __hip_bfloat16 b1 = __float2bfloat16(v.y); pk.us[1] = *(unsigned short*)&b1;
  __hip_bfloat16 b2 = __float2bfloat16(v.z); pk.us[2] = *(unsigned short*)&b2;
  __hip_bfloat16 b3 = __float2bfloat16(v.w); pk.us[3] = *(unsigned short*)&b3;
  *(uint2*)&Wb[i] = pk.u2;
  if (blockIdx.x == 0 && threadIdx.x < 128) {
    const int t = threadIdx.x;
    #pragma unroll
    for (int h = 0; h < 4; ++h) {
      float sl = 0.f;
      for (int d = 0; d < 32; ++d)
        sl += W[t * 128 + h * 32 + d] * a_l[h * 32 + d];
      wl[t * 4 + h] = sl;
    }
    if (t < 32) {
      const int et = t >> 2, h = t & 3;
      float acc = 0.f;
      for (int d = 0; d < 32; ++d) {
        float tmp = 0.f;
        for (int f = 0; f < 32; ++f)
          tmp += emb[et * 32 + f] * W_e[f * 128 + h * 32 + d];
        acc += a_e[h * 32 + d] * tmp;
      }
      he[et * 4 + h] = acc;
    }
  }
}

// ---------------- k1: h_l = head @ wl  (16-lane group per node, 4 nodes/wave) ----------
__global__ __launch_bounds__(256) void k1_hlr(const float* __restrict__ feat,
                                              const float* __restrict__ wv,
                                              float* __restrict__ o) {
  const int gid = blockIdx.x * 256 + threadIdx.x;   // grid exact: 6250*256 -> 100000 nodes
  const int node = gid >> 4, li = gid & 15;
  const float4* row = (const float4*)(feat + (size_t)node * 128 + li * 8);
  const float4 x0 = row[0], x1 = row[1];
  const float* w = wv + li * 32;                    // wl[d][4] for d = li*8 .. li*8+7
  float p0 = 0.f, p1 = 0.f, p2 = 0.f, p3 = 0.f;
  const float xs[8] = {x0.x, x0.y, x0.z, x0.w, x1.x, x1.y, x1.z, x1.w};
  #pragma unroll
  for (int j = 0; j < 8; ++j) {
    const float4 wj = *(const float4*)&w[j * 4];
    p0 += xs[j] * wj.x;
    p1 += xs[j] * wj.y;
    p2 += xs[j] * wj.z;
    p3 += xs[j] * wj.w;
  }
  #pragma unroll
  for (int m = 8; m; m >>= 1) {
    p0 += __shfl_xor(p0, m, 64);
    p1 += __shfl_xor(p1, m, 64);
    p2 += __shfl_xor(p2, m, 64);
    p3 += __shfl_xor(p3, m, 64);
  }
  if (li == 0) *(float4*)(o + (size_t)node * 4) = make_float4(p0, p1, p2, p3);
}

// ---------------- k2: h_tail = tail @ W (bf16) + h_r from epilogue; fp16 out ----------------
__global__ __launch_bounds__(256) void k2_gemm(const float* __restrict__ A,
                                               const __hip_bfloat16* __restrict__ Wb,
                                               const float* __restrict__ a_r,
                                               __half* __restrict__ out,
                                               float* __restrict__ h_r) {
  __shared__ __hip_bfloat16 sW[128 * 128];   // [k][c]
  __shared__ __hip_bfloat16 sA[128 * 68];    // [k][r]
  const int t = threadIdx.x;
  {
    const uint4* src = (const uint4*)Wb;
    uint4* dst = (uint4*)sW;
    #pragma unroll
    for (int i = 0; i < 8; ++i) dst[i * 256 + t] = src[i * 256 + t];
  }
  const int r0 = blockIdx.x * 64;
  #pragma unroll
  for (int ii = 0; ii < 8; ++ii) {
    const int i = ii * 256 + t;
    const int r = i >> 5, k4 = (i & 31) * 4;
    float4 v = make_float4(0.f, 0.f, 0.f, 0.f);
    if (r0 + r < N_TAILN) v = *(const float4*)&A[(size_t)(r0 + r) * 128 + k4];
    sA[(k4 + 0) * 68 + r] = __float2bfloat16(v.x);
    sA[(k4 + 1) * 68 + r] = __float2bfloat16(v.y);
    sA[(k4 + 2) * 68 + r] = __float2bfloat16(v.z);
    sA[(k4 + 3) * 68 + r] = __float2bfloat16(v.w);
  }
  __syncthreads();

  const int tc = t & 15, tr = t >> 4;
  const int c8 = tc * 8, r4 = tr * 4;
  float acc[4][8];
  #pragma unroll
  for (int i = 0; i < 4; ++i)
    #pragma unroll
    for (int j = 0; j < 8; ++j) acc[i][j] = 0.f;

  #pragma unroll 2
  for (int k = 0; k < 128; ++k) {
    const uint2 ab = *(const uint2*)&sA[k * 68 + r4];
    const float ar[4] = {__uint_as_float(ab.x << 16), __uint_as_float(ab.x & 0xffff0000u),
                         __uint_as_float(ab.y << 16), __uint_as_float(ab.y & 0xffff0000u)};
    const uint4 wbv = *(const uint4*)&sW[k * 128 + c8];
    float w[8];
    w[0] = __uint_as_float(wbv.x << 16); w[1] = __uint_as_float(wbv.x & 0xffff0000u);
    w[2] = __uint_as_float(wbv.y << 16); w[3] = __uint_as_float(wbv.y & 0xffff0000u);
    w[4] = __uint_as_float(wbv.z << 16); w[5] = __uint_as_float(wbv.z & 0xffff0000u);
    w[6] = __uint_as_float(wbv.w << 16); w[7] = __uint_as_float(wbv.w & 0xffff0000u);
    #pragma unroll
    for (int i = 0; i < 4; ++i)
      #pragma unroll
      for (int j = 0; j < 8; ++j)
        acc[i][j] += ar[i] * w[j];
  }

  // epilogue h_r: dot acc rows with a_r slice, reduce over the 4 tc's of this head
  const int hh = tc >> 2, d0 = (tc & 3) * 8;
  const float4 ar0 = *(const float4*)&a_r[hh * 32 + d0];
  const float4 ar1 = *(const float4*)&a_r[hh * 32 + d0 + 4];
  #pragma unroll
  for (int i = 0; i < 4; ++i) {
    float hr = acc[i][0] * ar0.x + acc[i][1] * ar0.y + acc[i][2] * ar0.z + acc[i][3] * ar0.w
             + acc[i][4] * ar1.x + acc[i][5] * ar1.y + acc[i][6] * ar1.z + acc[i][7] * ar1.w;
    hr += __shfl_xor(hr, 1, 64);
    hr += __shfl_xor(hr, 2, 64);
    if ((tc & 3) == 0 && (r0 + r4 + i) < N_TAILN)
      h_r[(size_t)(r0 + r4 + i) * 4 + hh] = hr;
  }

  #pragma unroll
  for (int i = 0; i < 4; ++i) {
    const int rr = r0 + r4 + i;
    if (rr < N_TAILN) {
      union { unsigned short us[8]; uint4 u4; } pk;
      #pragma unroll
      for (int j = 0; j < 8; ++j) {
        __half b = __float2half(acc[i][j]);
        pk.us[j] = *(unsigned short*)&b;
      }
      *(uint4*)&out[(size_t)rr * 128 + c8] = pk.u4;
    }
  }
}

// ---------------- p1: partition edges into 196 head-buckets (4B records) ----------------
// record = ti | et<<17 | hlocal<<20   (ti<2^17, et<8, hlocal<512)
// Grid 1250 blocks (5 edges/thread) -> ~4.9 blocks/CU, vs the old 250-block launch
// (<1 block/CU) that left the latency chains (atomics + scattered 4B stores) unhidden.
__global__ __launch_bounds__(256) void p1_part(const int* __restrict__ head_ind,
                                               const int* __restrict__ tail_ind,
                                               const int* __restrict__ etype,
                                               int* __restrict__ bucketCursor,
                                               unsigned int* __restrict__ recs) {
  __shared__ int hist[NB];
  const int t = threadIdx.x;
  for (int i = t; i < NB; i += 256) hist[i] = 0;
  __syncthreads();
  const int e0 = blockIdx.x * 1280;                  // 1250 blocks x 1280 = 1.6M
  int h[5];
  #pragma unroll
  for (int i = 0; i < 5; ++i) {
    h[i] = head_ind[e0 + i * 256 + t];
    atomicAdd(&hist[h[i] >> 9], 1);
  }
  __syncthreads();
  for (int i = t; i < NB; i += 256) {
    const int c = hist[i];
    hist[i] = (c > 0) ? atomicAdd(&bucketCursor[i], c) : 0;  // hist becomes running cursor
  }
  __syncthreads();
  #pragma unroll
  for (int i = 0; i < 5; ++i) {
    const int e = e0 + i * 256 + t;
    const int hi = h[i];
    const int b = hi >> 9;
    const int pos = atomicAdd(&hist[b], 1);
    recs[b * BCAP + pos] = (unsigned)tail_ind[e] | ((unsigned)etype[e] << 17)
                         | ((unsigned)(hi & 511) << 20);
  }
}

// ---------------- p23: fused {per-head CSR offsets} + {bucket -> CSR scatter} ----------
// One block (1024 threads, 16 waves) per bucket: build the 512-entry degree histogram,
// LDS-scan it into offsets (write off[] for k4), then scatter records through the same
// LDS cursors. Replaces the old p2_off + p3_scatter pair (196 blocks x 256 = 4 waves/CU)
// with 4x the waves/CU and one fewer launch.
__global__ __launch_bounds__(1024) void p23(const unsigned int* __restrict__ recs,
                                            const int* __restrict__ bucketCursor,
                                            int* __restrict__ off,
                                            int* __restrict__ pt) {
  __shared__ int cur[HPB];
  __shared__ int red[256];
  const int b = blockIdx.x, t = threadIdx.x;
  if (t < 256) red[t] = (t < b) ? bucketCursor[t] : 0;   // b <= 195 < 256
  if (t < HPB) cur[t] = 0;
  __syncthreads();
  for (int st = 128; st; st >>= 1) {                     // bstart = sum of earlier buckets
    if (t < st) red[t] += red[t + st];
    __syncthreads();
  }
  const int bstart = red[0];
  const int cnt = bucketCursor[b];
  const unsigned int* __restrict__ rb = recs + (size_t)b * BCAP;
  for (int i = t; i < cnt; i += 1024)
    atomicAdd(&cur[rb[i] >> 20], 1);
  __syncthreads();
  const int orig = (t < HPB) ? cur[t] : 0;
  for (int st = 1; st < HPB; st <<= 1) {                 // Hillis-Steele inclusive scan
    int v = 0;
    if (t < HPB && t >= st) v = cur[t - st];
    __syncthreads();
    if (t < HPB) cur[t] += v;
    __syncthreads();
  }
  const int h0 = b * HPB;
  if (t < HPB) {
    const int excl = bstart + cur[t] - orig;             // exclusive prefix
    cur[t] = excl;                                       // becomes scatter cursor
    if (h0 + t < N_HEADN) off[h0 + t] = excl;
  }
  if (b == NB - 1 && t == 0) off[N_HEADN] = NEDGE;
  __syncthreads();
  for (int i = t; i < cnt; i += 1024) {
    const unsigned r = rb[i];
    const int pos = atomicAdd(&cur[r >> 20], 1);
    pt[pos] = (int)(r & 0xFFFFFu);                       // ti | et<<17
  }
}

// ---------------- k4: 16-lane groups, 4 nodes/wave, fp16 gather + v_fma_mix ----------------
// (Round-1 version, measured 79.2 us / VGPR 40 / occ 54%.) NOTE (R3 post-mortem): do NOT
// pin min-waves via __launch_bounds__ — forcing VGPR<=32 spilled (+93MB scratch, 105us).
__global__ __launch_bounds__(256) void k4_agg(const int* __restrict__ off,
                                              const int* __restrict__ pt,
                                              const float* __restrict__ h_l,
                                              const float* __restrict__ h_r,
                                              const float* __restrict__ he,
                                              const __half* __restrict__ h_tail,
                                              float* __restrict__ out) {
  __shared__ __align__(16) float sw[4][4][72];   // [wave][group][li*4+h], stride 72 = conflict-free
  __shared__ int sti[4][4][20];                  // row byte-offsets, stride 20 = conflict-free
  __shared__ __align__(16) float4 she4[8];
  const int wid = threadIdx.x >> 6;
  const int lane = threadIdx.x & 63;
  const int g = lane >> 4, li = lane & 15;
  if (threadIdx.x < 8) she4[threadIdx.x] = ((const float4*)he)[threadIdx.x];
  __syncthreads();                               // only block barrier: she4 visibility
  const int n = blockIdx.x * 16 + wid * 4 + g;   // grid exact: 6250*16
  const int s = off[n], e = off[n + 1];
  const int nch = (e - s + 15) >> 4;
  const float4 hl = *(const float4*)(h_l + (size_t)n * 4);
  const int h = li >> 2;
  const unsigned dby = (unsigned)li * 16u;       // byte offset of lane's 8 dims (fp16)
  float m0 = -1e30f, m1 = -1e30f, m2 = -1e30f, m3 = -1e30f;
  float s0 = 0.f, s1 = 0.f, s2 = 0.f, s3 = 0.f;
  float acc[8];
  #pragma unroll
  for (int d = 0; d < 8; ++d) acc[d] = 0.f;
  float* __restrict__ swg = &sw[wid][g][0];
  int* __restrict__ stig = &sti[wid][g][0];
  const char* __restrict__ htb = (const char*)h_tail;
  for (int c = 0; c < nch; ++c) {
    const int base = s + (c << 4);
    const int rem = min(16, e - base);
    float a0 = -1e30f, a1 = -1e30f, a2 = -1e30f, a3 = -1e30f;
    if (li < rem) {
      const int pk = pt[base + li];
      const unsigned ti = (unsigned)pk & 0x1FFFFu;
      const int et = (pk >> 17) & 7;
      const float4 hr = *(const float4*)((const char*)h_r + (ti << 4));
      const float4 hv = she4[et];
      a0 = hl.x + hr.x + hv.x;
      a1 = hl.y + hr.y + hv.y;
      a2 = hl.z + hr.z + hv.z;
      a3 = hl.w + hr.w + hv.w;
      a0 = fmaxf(a0, SLOPE * a0);                // leaky relu (slope<1)
      a1 = fmaxf(a1, SLOPE * a1);
      a2 = fmaxf(a2, SLOPE * a2);
      a3 = fmaxf(a3, SLOPE * a3);
      stig[li] = (int)(ti << 8);                 // row byte offset (256 B/row)
    }
    float c0 = a0, c1 = a1, c2 = a2, c3 = a3;
    #pragma unroll
    for (int msk = 8; msk; msk >>= 1) {          // width-16 max trees
      c0 = fmaxf(c0, __shfl_xor(c0, msk, 64));
      c1 = fmaxf(c1, __shfl_xor(c1, msk, 64));
      c2 = fmaxf(c2, __shfl_xor(c2, msk, 64));
      c3 = fmaxf(c3, __shfl_xor(c3, msk, 64));
    }
    const float nm0 = fmaxf(m0, c0), nm1 = fmaxf(m1, c1);
    const float nm2 = fmaxf(m2, c2), nm3 = fmaxf(m3, c3);
    const float e0 = __expf(m0 - nm0), e1 = __expf(m1 - nm1);
    const float e2 = __expf(m2 - nm2), e3 = __expf(m3 - nm3);
    const float w0 = __expf(a0 - nm0), w1 = __expf(a1 - nm1);
    const float w2 = __expf(a2 - nm2), w3 = __expf(a3 - nm3);
    float t0 = w0, t1 = w1, t2 = w2, t3 = w3;
    #pragma unroll
    for (int msk = 8; msk; msk >>= 1) {          // width-16 sum trees
      t0 += __shfl_xor(t0, msk, 64);
      t1 += __shfl_xor(t1, msk, 64);
      t2 += __shfl_xor(t2, msk, 64);
      t3 += __shfl_xor(t3, msk, 64);
    }
    s0 = s0 * e0 + t0; s1 = s1 * e1 + t1;
    s2 = s2 * e2 + t2; s3 = s3 * e3 + t3;
    m0 = nm0; m1 = nm1; m2 = nm2; m3 = nm3;
    *(float4*)&swg[li * 4] = make_float4(w0, w1, w2, w3);  // w == 0 for li >= rem
    const float sc = (h == 0) ? e0 : (h == 1) ? e1 : (h == 2) ? e2 : e3;
    #pragma unroll
    for (int d = 0; d < 8; ++d) acc[d] *= sc;
    __builtin_amdgcn_wave_barrier();
    int j = 0;
    for (; j + 4 <= rem; j += 4) {
      const int o0 = stig[j], o1 = stig[j + 1], o2 = stig[j + 2], o3 = stig[j + 3];
      const float q0 = swg[(j + 0) * 4 + h];
      const float q1 = swg[(j + 1) * 4 + h];
      const float q2 = swg[(j + 2) * 4 + h];
      const float q3 = swg[(j + 3) * 4 + h];
      const uint4 v0 = *(const uint4*)(htb + (unsigned)o0 + dby);
      const uint4 v1 = *(const uint4*)(htb + (unsigned)o1 + dby);
      const uint4 v2 = *(const uint4*)(htb + (unsigned)o2 + dby);
      const uint4 v3 = *(const uint4*)(htb + (unsigned)o3 + dby);
      FMA_MIX_LO(acc[0], v0.x, q0); FMA_MIX_HI(acc[1], v0.x, q0);
      FMA_MIX_LO(acc[2], v0.y, q0); FMA_MIX_HI(acc[3], v0.y, q0);
      FMA_MIX_LO(acc[4], v0.z, q0); FMA_MIX_HI(acc[5], v0.z, q0);
      FMA_MIX_LO(acc[6], v0.w, q0); FMA_MIX_HI(acc[7], v0.w, q0);
      FMA_MIX_LO(acc[0], v1.x, q1); FMA_MIX_HI(acc[1], v1.x, q1);
      FMA_MIX_LO(acc[2], v1.y, q1); FMA_MIX_HI(acc[3], v1.y, q1);
      FMA_MIX_LO(acc[4], v1.z, q1); FMA_MIX_HI(acc[5], v1.z, q1);
      FMA_MIX_LO(acc[6], v1.w, q1); FMA_MIX_HI(acc[7], v1.w, q1);
      FMA_MIX_LO(acc[0], v2.x, q2); FMA_MIX_HI(acc[1], v2.x, q2);
      FMA_MIX_LO(acc[2], v2.y, q2); FMA_MIX_HI(acc[3], v2.y, q2);
      FMA_MIX_LO(acc[4], v2.z, q2); FMA_MIX_HI(acc[5], v2.z, q2);
      FMA_MIX_LO(acc[6], v2.w, q2); FMA_MIX_HI(acc[7], v2.w, q2);
      FMA_MIX_LO(acc[0], v3.x, q3); FMA_MIX_HI(acc[1], v3.x, q3);
      FMA_MIX_LO(acc[2], v3.y, q3); FMA_MIX_HI(acc[3], v3.y, q3);
      FMA_MIX_LO(acc[4], v3.z, q3); FMA_MIX_HI(acc[5], v3.z, q3);
      FMA_MIX_LO(acc[6], v3.w, q3); FMA_MIX_HI(acc[7], v3.w, q3);
    }
    for (; j < rem; ++j) {
      const int o = stig[j];
      const float q = swg[j * 4 + h];
      const uint4 v = *(const uint4*)(htb + (unsigned)o + dby);
      FMA_MIX_LO(acc[0], v.x, q); FMA_MIX_HI(acc[1], v.x, q);
      FMA_MIX_LO(acc[2], v.y, q); FMA_MIX_HI(acc[3], v.y, q);
      FMA_MIX_LO(acc[4], v.z, q); FMA_MIX_HI(acc[5], v.z, q);
      FMA_MIX_LO(acc[6], v.w, q); FMA_MIX_HI(acc[7], v.w, q);
    }
    __builtin_amdgcn_wave_barrier();
  }
  const float denom = (h == 0) ? s0 : (h == 1) ? s1 : (h == 2) ? s2 : s3;
  const float inv = denom > 0.f ? 1.f / denom : 0.f;
  float o[8];
  #pragma unroll
  for (int d = 0; d < 8; ++d) {
    const float v = acc[d] * inv;
    o[d] = v > 0.f ? v : expm1f(v);
  }
  float* op = out + (size_t)n * 128 + li * 8;
  *(float4*)op = make_float4(o[0], o[1], o[2], o[3]);
  *(float4*)(op + 4) = make_float4(o[4], o[5], o[6], o[7]);
}

extern "C" void kernel_launch(void* const* d_in, const int* in_sizes, int n_in,
                              void* d_out, int out_size, void* d_ws, size_t ws_size,
                              hipStream_t stream) {
  const float* head = (const float*)d_in[0];
  const float* tail = (const float*)d_in[1];
  const int* elist  = (const int*)d_in[2];
  const int* etype  = (const int*)d_in[3];
  const float* W    = (const float*)d_in[4];
  const float* W_e  = (const float*)d_in[5];
  const float* a_l  = (const float*)d_in[6];
  const float* a_r  = (const float*)d_in[7];
  const float* a_e  = (const float*)d_in[8];
  const float* emb  = (const float*)d_in[9];
  const int* head_ind = elist;
  const int* tail_ind = elist + NEDGE;
  (void)in_sizes; (void)n_in; (void)out_size; (void)ws_size;

  char* p = (char*)d_ws;
  size_t o = 0;
  auto carve = [&](size_t bytes) {
    char* r = p + o;
    o += (bytes + 255) & ~(size_t)255;
    return r;
  };
  // total ~42.6 MB
  __half* h_tail = (__half*)carve((size_t)N_TAILN * 128 * 2);                   // 25.6 MB
  int*   pt     = (int*)   carve((size_t)NEDGE * 4);                            // 6.4 MB
  unsigned int* recs = (unsigned int*)carve((size_t)NB * BCAP * 4);             // 7.2 MB
  float* h_l    = (float*) carve((size_t)N_HEADN * 4 * 4);                      // 1.6 MB
  float* h_r    = (float*) carve((size_t)N_TAILN * 4 * 4);                      // 1.6 MB
  int*   off    = (int*)   carve((size_t)(N_HEADN + 1) * 4);                    // 0.4 MB
  int*   bucketCursor = (int*)carve(NB * 4);
  float* wl     = (float*) carve(128 * 4 * 4);
  float* he     = (float*) carve(8 * 4 * 4);
  __hip_bfloat16* Wb = (__hip_bfloat16*)carve(16384 * 2);                       // 32 KB

  hipMemsetAsync(bucketCursor, 0, NB * sizeof(int), stream);
  k0m<<<16, 256, 0, stream>>>(W, W_e, a_l, a_e, emb, Wb, wl, he);
  k1_hlr<<<(N_HEADN * 16) / 256, 256, 0, stream>>>(head, wl, h_l);
  k2_gemm<<<(N_TAILN + 63) / 64, 256, 0, stream>>>(tail, Wb, a_r, h_tail, h_r);
  p1_part<<<NEDGE / 1280, 256, 0, stream>>>(head_ind, tail_ind, etype, bucketCursor, recs);
  p23<<<NB, 1024, 0, stream>>>(recs, bucketCursor, off, pt);
  k4_agg<<<N_HEADN / 16, 256, 0, stream>>>(off, pt, h_l, h_r, he, h_tail, (float*)d_out);
}

// Round 11
// 327.212 us; speedup vs baseline: 1.1135x; 1.1135x over previous
//
#include <hip/hip_runtime.h>
#include <hip/hip_bf16.h>
#include <hip/hip_fp16.h>
#include <math.h>

#define N_HEADN 100000
#define N_TAILN 100000
#define NEDGE   1600000
#define SLOPE   0.2f

#define NB   196      // buckets: head>>9
#define HPB  512      // heads per bucket
#define BCAP 9216     // bucket capacity (mean 8191, sigma ~90; 9216 = +11 sigma)

static __device__ __forceinline__ float bf2f(__hip_bfloat16 x) { return __bfloat162float(x); }

// f16 source (lo/hi half of packed u32), fp32 multiplier + fp32 accumulate, 1 instr/dim
#define FMA_MIX_LO(acc, pk, q) \
  asm("v_fma_mix_f32 %0, %1, %2, %0 op_sel_hi:[1,0,0]" : "+v"(acc) : "v"(pk), "v"(q))
#define FMA_MIX_HI(acc, pk, q) \
  asm("v_fma_mix_f32 %0, %1, %2, %0 op_sel:[1,0,0] op_sel_hi:[1,0,0]" : "+v"(acc) : "v"(pk), "v"(q))

typedef __attribute__((ext_vector_type(8))) short bfrag;   // 8 bf16 (4 VGPRs)
typedef __attribute__((ext_vector_type(4))) float ffrag;   // 4 fp32 acc

// ---------------- k0m: { W -> bf16 TRANSPOSED } + { wl[128][4], he[8][4] prep } ----------
// WbT[c][k] = bf16(W[k][c]) so k2's MFMA B-fragment (8 contiguous k) is one b128 read.
__global__ __launch_bounds__(256) void k0m(const float* __restrict__ W,
                                           const float* __restrict__ W_e,
                                           const float* __restrict__ a_l,
                                           const float* __restrict__ a_e,
                                           const float* __restrict__ emb,
                                           __hip_bfloat16* __restrict__ WbT,
                                           float* __restrict__ wl,
                                           float* __restrict__ he) {
  const int i = (blockIdx.x * 256 + threadIdx.x) * 4;   // 4 consecutive W elems (same row)
  const int r = i >> 7, c = i & 127;
  const float4 v = *(const float4*)&W[i];
  WbT[(size_t)(c + 0) * 128 + r] = __float2bfloat16(v.x);
  WbT[(size_t)(c + 1) * 128 + r] = __float2bfloat16(v.y);
  WbT[(size_t)(c + 2) * 128 + r] = __float2bfloat16(v.z);
  WbT[(size_t)(c + 3) * 128 + r] = __float2bfloat16(v.w);
  if (blockIdx.x == 0 && threadIdx.x < 128) {
    const int t = threadIdx.x;
    #pragma unroll
    for (int h = 0; h < 4; ++h) {
      float sl = 0.f;
      for (int d = 0; d < 32; ++d)
        sl += W[t * 128 + h * 32 + d] * a_l[h * 32 + d];
      wl[t * 4 + h] = sl;
    }
    if (t < 32) {
      const int et = t >> 2, h = t & 3;
      float acc = 0.f;
      for (int d = 0; d < 32; ++d) {
        float tmp = 0.f;
        for (int f = 0; f < 32; ++f)
          tmp += emb[et * 32 + f] * W_e[f * 128 + h * 32 + d];
        acc += a_e[h * 32 + d] * tmp;
      }
      he[et * 4 + h] = acc;
    }
  }
}

// ---------------- k1: h_l = head @ wl  (16-lane group per node, 4 nodes/wave) ----------
__global__ __launch_bounds__(256) void k1_hlr(const float* __restrict__ feat,
                                              const float* __restrict__ wv,
                                              float* __restrict__ o) {
  const int gid = blockIdx.x * 256 + threadIdx.x;   // grid exact: 6250*256 -> 100000 nodes
  const int node = gid >> 4, li = gid & 15;
  const float4* row = (const float4*)(feat + (size_t)node * 128 + li * 8);
  const float4 x0 = row[0], x1 = row[1];
  const float* w = wv + li * 32;                    // wl[d][4] for d = li*8 .. li*8+7
  float p0 = 0.f, p1 = 0.f, p2 = 0.f, p3 = 0.f;
  const float xs[8] = {x0.x, x0.y, x0.z, x0.w, x1.x, x1.y, x1.z, x1.w};
  #pragma unroll
  for (int j = 0; j < 8; ++j) {
    const float4 wj = *(const float4*)&w[j * 4];
    p0 += xs[j] * wj.x;
    p1 += xs[j] * wj.y;
    p2 += xs[j] * wj.z;
    p3 += xs[j] * wj.w;
  }
  #pragma unroll
  for (int m = 8; m; m >>= 1) {
    p0 += __shfl_xor(p0, m, 64);
    p1 += __shfl_xor(p1, m, 64);
    p2 += __shfl_xor(p2, m, 64);
    p3 += __shfl_xor(p3, m, 64);
  }
  if (li == 0) *(float4*)(o + (size_t)node * 4) = make_float4(p0, p1, p2, p3);
}

// ---------------- k2: h_tail = tail @ W via MFMA (bf16 in, fp32 acc); fp16 out + h_r ----
// 4 waves/block, wave w owns rows r0+16w..+15. Per wave: 8 col-tiles x 4 K-chunks = 32x
// mfma_f32_16x16x32_bf16. A-frag from global fp32 (2 float4/lane/chunk, packed to bf16);
// B-frag = one ds_read_b128 from padded sBT[128][136] (WbT staged, 2-way aliasing only).
// Layouts (m89-verified family): a[l][i]=A[l&15][(l>>4)*8+i]; b[l][i]=B[(l>>4)*8+i][l&15];
// d: row=(l>>4)*4+i, col=l&15.
__global__ __launch_bounds__(256) void k2_gemm(const float* __restrict__ A,
                                               const __hip_bfloat16* __restrict__ WbT,
                                               const float* __restrict__ a_r,
                                               __half* __restrict__ out,
                                               float* __restrict__ h_r) {
  __shared__ __hip_bfloat16 sBT[128 * 136];   // [c][k], stride 136 (272B = 16B-aligned rows)
  __shared__ float sAr[128];
  const int t = threadIdx.x;
  {
    const uint4* src = (const uint4*)WbT;     // contiguous in k
    #pragma unroll
    for (int it = 0; it < 8; ++it) {
      const int i = it * 256 + t;             // chunk i: c = i>>4, k0 = (i&15)*8
      *(uint4*)&sBT[(i >> 4) * 136 + (i & 15) * 8] = src[i];
    }
  }
  if (t < 128) sAr[t] = a_r[t];
  __syncthreads();

  const int w = t >> 6, l = t & 63;
  const int lm = l & 15, kg = l >> 4;
  const int row = blockIdx.x * 64 + w * 16 + lm;
  const int rowc = row < N_TAILN ? row : N_TAILN - 1;
  const float* __restrict__ Arow = A + (size_t)rowc * 128 + kg * 8;

  ffrag acc[8];
  #pragma unroll
  for (int nt = 0; nt < 8; ++nt) acc[nt] = (ffrag){0.f, 0.f, 0.f, 0.f};

  #pragma unroll
  for (int kc = 0; kc < 4; ++kc) {
    const float4 va = *(const float4*)(Arow + kc * 32);
    const float4 vb = *(const float4*)(Arow + kc * 32 + 4);
    union { unsigned short us[8]; bfrag v; } af;
    __hip_bfloat16 b;
    b = __float2bfloat16(va.x); af.us[0] = *(unsigned short*)&b;
    b = __float2bfloat16(va.y); af.us[1] = *(unsigned short*)&b;
    b = __float2bfloat16(va.z); af.us[2] = *(unsigned short*)&b;
    b = __float2bfloat16(va.w); af.us[3] = *(unsigned short*)&b;
    b = __float2bfloat16(vb.x); af.us[4] = *(unsigned short*)&b;
    b = __float2bfloat16(vb.y); af.us[5] = *(unsigned short*)&b;
    b = __float2bfloat16(vb.z); af.us[6] = *(unsigned short*)&b;
    b = __float2bfloat16(vb.w); af.us[7] = *(unsigned short*)&b;
    const int kb = kc * 32 + kg * 8;
    #pragma unroll
    for (int nt = 0; nt < 8; ++nt) {
      const bfrag bf = *(const bfrag*)&sBT[(nt * 16 + lm) * 136 + kb];
      acc[nt] = __builtin_amdgcn_mfma_f32_16x16x32_bf16(af.v, bf, acc[nt], 0, 0, 0);
    }
  }

  // epilogue h_r: per-head (head = nt>>1) partials, butterfly over the 16-lane row-group
  float ph[4][4];                            // [head][i] — static indexing (rule #20)
  #pragma unroll
  for (int hh = 0; hh < 4; ++hh)
    #pragma unroll
    for (int i = 0; i < 4; ++i) ph[hh][i] = 0.f;
  #pragma unroll
  for (int nt = 0; nt < 8; ++nt) {
    const float ar = sAr[nt * 16 + lm];
    #pragma unroll
    for (int i = 0; i < 4; ++i) ph[nt >> 1][i] += acc[nt][i] * ar;
  }
  #pragma unroll
  for (int hh = 0; hh < 4; ++hh)
    #pragma unroll
    for (int i = 0; i < 4; ++i) {
      ph[hh][i] += __shfl_xor(ph[hh][i], 1, 64);
      ph[hh][i] += __shfl_xor(ph[hh][i], 2, 64);
      ph[hh][i] += __shfl_xor(ph[hh][i], 4, 64);
      ph[hh][i] += __shfl_xor(ph[hh][i], 8, 64);
    }
  if (lm == 0) {
    #pragma unroll
    for (int i = 0; i < 4; ++i) {
      const int rr = blockIdx.x * 64 + w * 16 + kg * 4 + i;
      if (rr < N_TAILN)
        *(float4*)&h_r[(size_t)rr * 4] = make_float4(ph[0][i], ph[1][i], ph[2][i], ph[3][i]);
    }
  }

  // C store (fp16): lane holds D rows kg*4+i, col lm of each 16-col tile
  #pragma unroll
  for (int i = 0; i < 4; ++i) {
    const int rr = blockIdx.x * 64 + w * 16 + kg * 4 + i;
    if (rr < N_TAILN) {
      __half* orow = out + (size_t)rr * 128 + lm;
      #pragma unroll
      for (int nt = 0; nt < 8; ++nt)
        orow[nt * 16] = __float2half(acc[nt][i]);
    }
  }
}

// ---------------- p1: partition edges into 196 head-buckets (4B records) ----------------
// record = ti | et<<17 | hlocal<<20   (ti<2^17, et<8, hlocal<512)
__global__ __launch_bounds__(256) void p1_part(const int* __restrict__ head_ind,
                                               const int* __restrict__ tail_ind,
                                               const int* __restrict__ etype,
                                               int* __restrict__ bucketCursor,
                                               unsigned int* __restrict__ recs) {
  __shared__ int hist[NB];
  const int t = threadIdx.x;
  for (int i = t; i < NB; i += 256) hist[i] = 0;
  __syncthreads();
  const int e0 = blockIdx.x * 1280;                  // 1250 blocks x 1280 = 1.6M
  int h[5];
  #pragma unroll
  for (int i = 0; i < 5; ++i) {
    h[i] = head_ind[e0 + i * 256 + t];
    atomicAdd(&hist[h[i] >> 9], 1);
  }
  __syncthreads();
  for (int i = t; i < NB; i += 256) {
    const int c = hist[i];
    hist[i] = (c > 0) ? atomicAdd(&bucketCursor[i], c) : 0;  // hist becomes running cursor
  }
  __syncthreads();
  #pragma unroll
  for (int i = 0; i < 5; ++i) {
    const int e = e0 + i * 256 + t;
    const int hi = h[i];
    const int b = hi >> 9;
    const int pos = atomicAdd(&hist[b], 1);
    recs[b * BCAP + pos] = (unsigned)tail_ind[e] | ((unsigned)etype[e] << 17)
                         | ((unsigned)(hi & 511) << 20);
  }
}

// ---------------- p23: fused {per-head CSR offsets} + {bucket -> CSR scatter} ----------
__global__ __launch_bounds__(1024) void p23(const unsigned int* __restrict__ recs,
                                            const int* __restrict__ bucketCursor,
                                            int* __restrict__ off,
                                            int* __restrict__ pt) {
  __shared__ int cur[HPB];
  __shared__ int red[256];
  const int b = blockIdx.x, t = threadIdx.x;
  if (t < 256) red[t] = (t < b) ? bucketCursor[t] : 0;   // b <= 195 < 256
  if (t < HPB) cur[t] = 0;
  __syncthreads();
  for (int st = 128; st; st >>= 1) {                     // bstart = sum of earlier buckets
    if (t < st) red[t] += red[t + st];
    __syncthreads();
  }
  const int bstart = red[0];
  const int cnt = bucketCursor[b];
  const unsigned int* __restrict__ rb = recs + (size_t)b * BCAP;
  for (int i = t; i < cnt; i += 1024)
    atomicAdd(&cur[rb[i] >> 20], 1);
  __syncthreads();
  const int orig = (t < HPB) ? cur[t] : 0;
  for (int st = 1; st < HPB; st <<= 1) {                 // Hillis-Steele inclusive scan
    int v = 0;
    if (t < HPB && t >= st) v = cur[t - st];
    __syncthreads();
    if (t < HPB) cur[t] += v;
    __syncthreads();
  }
  const int h0 = b * HPB;
  if (t < HPB) {
    const int excl = bstart + cur[t] - orig;             // exclusive prefix
    cur[t] = excl;                                       // becomes scatter cursor
    if (h0 + t < N_HEADN) off[h0 + t] = excl;
  }
  if (b == NB - 1 && t == 0) off[N_HEADN] = NEDGE;
  __syncthreads();
  for (int i = t; i < cnt; i += 1024) {
    const unsigned r = rb[i];
    const int pos = atomicAdd(&cur[r >> 20], 1);
    pt[pos] = (int)(r & 0xFFFFFu);                       // ti | et<<17
  }
}

// ---------------- k4: 16-lane groups, 4 nodes/wave, fp16 gather + v_fma_mix ----------------
// (Round-1 version, measured 79.2 us / VGPR 40 / occ 54%.) NOTE (R3 post-mortem): do NOT
// pin min-waves via __launch_bounds__ — forcing VGPR<=32 spilled (+93MB scratch, 105us).
__global__ __launch_bounds__(256) void k4_agg(const int* __restrict__ off,
                                              const int* __restrict__ pt,
                                              const float* __restrict__ h_l,
                                              const float* __restrict__ h_r,
                                              const float* __restrict__ he,
                                              const __half* __restrict__ h_tail,
                                              float* __restrict__ out) {
  __shared__ __align__(16) float sw[4][4][72];   // [wave][group][li*4+h], stride 72 = conflict-free
  __shared__ int sti[4][4][20];                  // row byte-offsets, stride 20 = conflict-free
  __shared__ __align__(16) float4 she4[8];
  const int wid = threadIdx.x >> 6;
  const int lane = threadIdx.x & 63;
  const int g = lane >> 4, li = lane & 15;
  if (threadIdx.x < 8) she4[threadIdx.x] = ((const float4*)he)[threadIdx.x];
  __syncthreads();                               // only block barrier: she4 visibility
  const int n = blockIdx.x * 16 + wid * 4 + g;   // grid exact: 6250*16
  const int s = off[n], e = off[n + 1];
  const int nch = (e - s + 15) >> 4;
  const float4 hl = *(const float4*)(h_l + (size_t)n * 4);
  const int h = li >> 2;
  const unsigned dby = (unsigned)li * 16u;       // byte offset of lane's 8 dims (fp16)
  float m0 = -1e30f, m1 = -1e30f, m2 = -1e30f, m3 = -1e30f;
  float s0 = 0.f, s1 = 0.f, s2 = 0.f, s3 = 0.f;
  float acc[8];
  #pragma unroll
  for (int d = 0; d < 8; ++d) acc[d] = 0.f;
  float* __restrict__ swg = &sw[wid][g][0];
  int* __restrict__ stig = &sti[wid][g][0];
  const char* __restrict__ htb = (const char*)h_tail;
  for (int c = 0; c < nch; ++c) {
    const int base = s + (c << 4);
    const int rem = min(16, e - base);
    float a0 = -1e30f, a1 = -1e30f, a2 = -1e30f, a3 = -1e30f;
    if (li < rem) {
      const int pk = pt[base + li];
      const unsigned ti = (unsigned)pk & 0x1FFFFu;
      const int et = (pk >> 17) & 7;
      const float4 hr = *(const float4*)((const char*)h_r + (ti << 4));
      const float4 hv = she4[et];
      a0 = hl.x + hr.x + hv.x;
      a1 = hl.y + hr.y + hv.y;
      a2 = hl.z + hr.z + hv.z;
      a3 = hl.w + hr.w + hv.w;
      a0 = fmaxf(a0, SLOPE * a0);                // leaky relu (slope<1)
      a1 = fmaxf(a1, SLOPE * a1);
      a2 = fmaxf(a2, SLOPE * a2);
      a3 = fmaxf(a3, SLOPE * a3);
      stig[li] = (int)(ti << 8);                 // row byte offset (256 B/row)
    }
    float c0 = a0, c1 = a1, c2 = a2, c3 = a3;
    #pragma unroll
    for (int msk = 8; msk; msk >>= 1) {          // width-16 max trees
      c0 = fmaxf(c0, __shfl_xor(c0, msk, 64));
      c1 = fmaxf(c1, __shfl_xor(c1, msk, 64));
      c2 = fmaxf(c2, __shfl_xor(c2, msk, 64));
      c3 = fmaxf(c3, __shfl_xor(c3, msk, 64));
    }
    const float nm0 = fmaxf(m0, c0), nm1 = fmaxf(m1, c1);
    const float nm2 = fmaxf(m2, c2), nm3 = fmaxf(m3, c3);
    const float e0 = __expf(m0 - nm0), e1 = __expf(m1 - nm1);
    const float e2 = __expf(m2 - nm2), e3 = __expf(m3 - nm3);
    const float w0 = __expf(a0 - nm0), w1 = __expf(a1 - nm1);
    const float w2 = __expf(a2 - nm2), w3 = __expf(a3 - nm3);
    float t0 = w0, t1 = w1, t2 = w2, t3 = w3;
    #pragma unroll
    for (int msk = 8; msk; msk >>= 1) {          // width-16 sum trees
      t0 += __shfl_xor(t0, msk, 64);
      t1 += __shfl_xor(t1, msk, 64);
      t2 += __shfl_xor(t2, msk, 64);
      t3 += __shfl_xor(t3, msk, 64);
    }
    s0 = s0 * e0 + t0; s1 = s1 * e1 + t1;
    s2 = s2 * e2 + t2; s3 = s3 * e3 + t3;
    m0 = nm0; m1 = nm1; m2 = nm2; m3 = nm3;
    *(float4*)&swg[li * 4] = make_float4(w0, w1, w2, w3);  // w == 0 for li >= rem
    const float sc = (h == 0) ? e0 : (h == 1) ? e1 : (h == 2) ? e2 : e3;
    #pragma unroll
    for (int d = 0; d < 8; ++d) acc[d] *= sc;
    __builtin_amdgcn_wave_barrier();
    int j = 0;
    for (; j + 4 <= rem; j += 4) {
      const int o0 = stig[j], o1 = stig[j + 1], o2 = stig[j + 2], o3 = stig[j + 3];
      const float q0 = swg[(j + 0) * 4 + h];
      const float q1 = swg[(j + 1) * 4 + h];
      const float q2 = swg[(j + 2) * 4 + h];
      const float q3 = swg[(j + 3) * 4 + h];
      const uint4 v0 = *(const uint4*)(htb + (unsigned)o0 + dby);
      const uint4 v1 = *(const uint4*)(htb + (unsigned)o1 + dby);
      const uint4 v2 = *(const uint4*)(htb + (unsigned)o2 + dby);
      const uint4 v3 = *(const uint4*)(htb + (unsigned)o3 + dby);
      FMA_MIX_LO(acc[0], v0.x, q0); FMA_MIX_HI(acc[1], v0.x, q0);
      FMA_MIX_LO(acc[2], v0.y, q0); FMA_MIX_HI(acc[3], v0.y, q0);
      FMA_MIX_LO(acc[4], v0.z, q0); FMA_MIX_HI(acc[5], v0.z, q0);
      FMA_MIX_LO(acc[6], v0.w, q0); FMA_MIX_HI(acc[7], v0.w, q0);
      FMA_MIX_LO(acc[0], v1.x, q1); FMA_MIX_HI(acc[1], v1.x, q1);
      FMA_MIX_LO(acc[2], v1.y, q1); FMA_MIX_HI(acc[3], v1.y, q1);
      FMA_MIX_LO(acc[4], v1.z, q1); FMA_MIX_HI(acc[5], v1.z, q1);
      FMA_MIX_LO(acc[6], v1.w, q1); FMA_MIX_HI(acc[7], v1.w, q1);
      FMA_MIX_LO(acc[0], v2.x, q2); FMA_MIX_HI(acc[1], v2.x, q2);
      FMA_MIX_LO(acc[2], v2.y, q2); FMA_MIX_HI(acc[3], v2.y, q2);
      FMA_MIX_LO(acc[4], v2.z, q2); FMA_MIX_HI(acc[5], v2.z, q2);
      FMA_MIX_LO(acc[6], v2.w, q2); FMA_MIX_HI(acc[7], v2.w, q2);
      FMA_MIX_LO(acc[0], v3.x, q3); FMA_MIX_HI(acc[1], v3.x, q3);
      FMA_MIX_LO(acc[2], v3.y, q3); FMA_MIX_HI(acc[3], v3.y, q3);
      FMA_MIX_LO(acc[4], v3.z, q3); FMA_MIX_HI(acc[5], v3.z, q3);
      FMA_MIX_LO(acc[6], v3.w, q3); FMA_MIX_HI(acc[7], v3.w, q3);
    }
    for (; j < rem; ++j) {
      const int o = stig[j];
      const float q = swg[j * 4 + h];
      const uint4 v = *(const uint4*)(htb + (unsigned)o + dby);
      FMA_MIX_LO(acc[0], v.x, q); FMA_MIX_HI(acc[1], v.x, q);
      FMA_MIX_LO(acc[2], v.y, q); FMA_MIX_HI(acc[3], v.y, q);
      FMA_MIX_LO(acc[4], v.z, q); FMA_MIX_HI(acc[5], v.z, q);
      FMA_MIX_LO(acc[6], v.w, q); FMA_MIX_HI(acc[7], v.w, q);
    }
    __builtin_amdgcn_wave_barrier();
  }
  const float denom = (h == 0) ? s0 : (h == 1) ? s1 : (h == 2) ? s2 : s3;
  const float inv = denom > 0.f ? 1.f / denom : 0.f;
  float o[8];
  #pragma unroll
  for (int d = 0; d < 8; ++d) {
    const float v = acc[d] * inv;
    o[d] = v > 0.f ? v : expm1f(v);
  }
  float* op = out + (size_t)n * 128 + li * 8;
  *(float4*)op = make_float4(o[0], o[1], o[2], o[3]);
  *(float4*)(op + 4) = make_float4(o[4], o[5], o[6], o[7]);
}

extern "C" void kernel_launch(void* const* d_in, const int* in_sizes, int n_in,
                              void* d_out, int out_size, void* d_ws, size_t ws_size,
                              hipStream_t stream) {
  const float* head = (const float*)d_in[0];
  const float* tail = (const float*)d_in[1];
  const int* elist  = (const int*)d_in[2];
  const int* etype  = (const int*)d_in[3];
  const float* W    = (const float*)d_in[4];
  const float* W_e  = (const float*)d_in[5];
  const float* a_l  = (const float*)d_in[6];
  const float* a_r  = (const float*)d_in[7];
  const float* a_e  = (const float*)d_in[8];
  const float* emb  = (const float*)d_in[9];
  const int* head_ind = elist;
  const int* tail_ind = elist + NEDGE;
  (void)in_sizes; (void)n_in; (void)out_size; (void)ws_size;

  char* p = (char*)d_ws;
  size_t o = 0;
  auto carve = [&](size_t bytes) {
    char* r = p + o;
    o += (bytes + 255) & ~(size_t)255;
    return r;
  };
  // total ~42.6 MB
  __half* h_tail = (__half*)carve((size_t)N_TAILN * 128 * 2);                   // 25.6 MB
  int*   pt     = (int*)   carve((size_t)NEDGE * 4);                            // 6.4 MB
  unsigned int* recs = (unsigned int*)carve((size_t)NB * BCAP * 4);             // 7.2 MB
  float* h_l    = (float*) carve((size_t)N_HEADN * 4 * 4);                      // 1.6 MB
  float* h_r    = (float*) carve((size_t)N_TAILN * 4 * 4);                      // 1.6 MB
  int*   off    = (int*)   carve((size_t)(N_HEADN + 1) * 4);                    // 0.4 MB
  int*   bucketCursor = (int*)carve(NB * 4);
  float* wl     = (float*) carve(128 * 4 * 4);
  float* he     = (float*) carve(8 * 4 * 4);
  __hip_bfloat16* WbT = (__hip_bfloat16*)carve(16384 * 2);                      // 32 KB

  hipMemsetAsync(bucketCursor, 0, NB * sizeof(int), stream);
  k0m<<<16, 256, 0, stream>>>(W, W_e, a_l, a_e, emb, WbT, wl, he);
  k1_hlr<<<(N_HEADN * 16) / 256, 256, 0, stream>>>(head, wl, h_l);
  k2_gemm<<<(N_TAILN + 63) / 64, 256, 0, stream>>>(tail, WbT, a_r, h_tail, h_r);
  p1_part<<<NEDGE / 1280, 256, 0, stream>>>(head_ind, tail_ind, etype, bucketCursor, recs);
  p23<<<NB, 1024, 0, stream>>>(recs, bucketCursor, off, pt);
  k4_agg<<<N_HEADN / 16, 256, 0, stream>>>(off, pt, h_l, h_r, he, h_tail, (float*)d_out);
}

// Round 12
// 303.737 us; speedup vs baseline: 1.1996x; 1.0773x over previous
//
#include <hip/hip_runtime.h>
#include <hip/hip_bf16.h>
#include <hip/hip_fp16.h>
#include <math.h>

#define N_HEADN 100000
#define N_TAILN 100000
#define NEDGE   1600000
#define SLOPE   0.2f

#define NB   196      // buckets: head>>9
#define HPB  512      // heads per bucket
#define BCAP 9216     // bucket capacity (mean 8191, sigma ~90; 9216 = +11 sigma)

// fusedA role ranges
#define FB_K2 1563    // k2 role: 1563 blocks x 64 rows
#define FB_P1 1250    // p1 role: 1250 blocks x 1280 edges
#define FB_K1 6250    // k1 role: 6250 blocks x 16 nodes

static __device__ __forceinline__ float bf2f(__hip_bfloat16 x) { return __bfloat162float(x); }

// f16 source (lo/hi half of packed u32), fp32 multiplier + fp32 accumulate, 1 instr/dim
#define FMA_MIX_LO(acc, pk, q) \
  asm("v_fma_mix_f32 %0, %1, %2, %0 op_sel_hi:[1,0,0]" : "+v"(acc) : "v"(pk), "v"(q))
#define FMA_MIX_HI(acc, pk, q) \
  asm("v_fma_mix_f32 %0, %1, %2, %0 op_sel:[1,0,0] op_sel_hi:[1,0,0]" : "+v"(acc) : "v"(pk), "v"(q))

typedef __attribute__((ext_vector_type(8))) short bfrag;   // 8 bf16 (4 VGPRs)
typedef __attribute__((ext_vector_type(4))) float ffrag;   // 4 fp32 acc

// ---------------- k0m: { W -> bf16 TRANSPOSED } + { wl[128][4], he[8][4] prep } ----------
__global__ __launch_bounds__(256) void k0m(const float* __restrict__ W,
                                           const float* __restrict__ W_e,
                                           const float* __restrict__ a_l,
                                           const float* __restrict__ a_e,
                                           const float* __restrict__ emb,
                                           __hip_bfloat16* __restrict__ WbT,
                                           float* __restrict__ wl,
                                           float* __restrict__ he) {
  const int i = (blockIdx.x * 256 + threadIdx.x) * 4;   // 4 consecutive W elems (same row)
  const int r = i >> 7, c = i & 127;
  const float4 v = *(const float4*)&W[i];
  WbT[(size_t)(c + 0) * 128 + r] = __float2bfloat16(v.x);
  WbT[(size_t)(c + 1) * 128 + r] = __float2bfloat16(v.y);
  WbT[(size_t)(c + 2) * 128 + r] = __float2bfloat16(v.z);
  WbT[(size_t)(c + 3) * 128 + r] = __float2bfloat16(v.w);
  if (blockIdx.x == 0 && threadIdx.x < 128) {
    const int t = threadIdx.x;
    #pragma unroll
    for (int h = 0; h < 4; ++h) {
      float sl = 0.f;
      for (int d = 0; d < 32; ++d)
        sl += W[t * 128 + h * 32 + d] * a_l[h * 32 + d];
      wl[t * 4 + h] = sl;
    }
    if (t < 32) {
      const int et = t >> 2, h = t & 3;
      float acc = 0.f;
      for (int d = 0; d < 32; ++d) {
        float tmp = 0.f;
        for (int f = 0; f < 32; ++f)
          tmp += emb[et * 32 + f] * W_e[f * 128 + h * 32 + d];
        acc += a_e[h * 32 + d] * tmp;
      }
      he[et * 4 + h] = acc;
    }
  }
}

// ---------------- fusedA: role-switched { k2-MFMA | p1-partition | k1-h_l } -------------
// The three mid-pipeline kernels are mutually independent (k2: tail->h_tail/h_r;
// p1: elist->recs; k1: head->h_l). One launch co-schedules them: MFMA-heavy k2 and
// atomic-heavy p1 dispatch first, BW-bound k1 fills the machine behind them.
// Shared LDS arena = max(role needs): k2 uses 128*136*2 + 512 B; p1 uses 784 B; k1 none.
__global__ __launch_bounds__(256) void fusedA(
    const float* __restrict__ A,            // tail features (k2)
    const __hip_bfloat16* __restrict__ WbT,
    const float* __restrict__ a_r,
    __half* __restrict__ out,               // h_tail fp16
    float* __restrict__ h_r,
    const int* __restrict__ head_ind,       // p1
    const int* __restrict__ tail_ind,
    const int* __restrict__ etype,
    int* __restrict__ bucketCursor,
    unsigned int* __restrict__ recs,
    const float* __restrict__ feat,         // head features (k1)
    const float* __restrict__ wv,           // wl
    float* __restrict__ o) {                // h_l
  __shared__ __align__(16) char smem[128 * 136 * 2 + 512];
  const int bid = blockIdx.x;
  const int t = threadIdx.x;

  if (bid < FB_K2) {
    // ================= k2 role: h_tail = tail @ W via MFMA + h_r epilogue ==============
    __hip_bfloat16* sBT = (__hip_bfloat16*)smem;       // [c][k], stride 136
    float* sAr = (float*)(smem + 128 * 136 * 2);
    {
      const uint4* src = (const uint4*)WbT;            // contiguous in k
      #pragma unroll
      for (int it = 0; it < 8; ++it) {
        const int i = it * 256 + t;                    // chunk i: c = i>>4, k0 = (i&15)*8
        *(uint4*)&sBT[(i >> 4) * 136 + (i & 15) * 8] = src[i];
      }
    }
    if (t < 128) sAr[t] = a_r[t];
    __syncthreads();

    const int w = t >> 6, l = t & 63;
    const int lm = l & 15, kg = l >> 4;
    const int row = bid * 64 + w * 16 + lm;
    const int rowc = row < N_TAILN ? row : N_TAILN - 1;
    const float* __restrict__ Arow = A + (size_t)rowc * 128 + kg * 8;

    ffrag acc[8];
    #pragma unroll
    for (int nt = 0; nt < 8; ++nt) acc[nt] = (ffrag){0.f, 0.f, 0.f, 0.f};

    #pragma unroll
    for (int kc = 0; kc < 4; ++kc) {
      const float4 va = *(const float4*)(Arow + kc * 32);
      const float4 vb = *(const float4*)(Arow + kc * 32 + 4);
      union { unsigned short us[8]; bfrag v; } af;
      __hip_bfloat16 b;
      b = __float2bfloat16(va.x); af.us[0] = *(unsigned short*)&b;
      b = __float2bfloat16(va.y); af.us[1] = *(unsigned short*)&b;
      b = __float2bfloat16(va.z); af.us[2] = *(unsigned short*)&b;
      b = __float2bfloat16(va.w); af.us[3] = *(unsigned short*)&b;
      b = __float2bfloat16(vb.x); af.us[4] = *(unsigned short*)&b;
      b = __float2bfloat16(vb.y); af.us[5] = *(unsigned short*)&b;
      b = __float2bfloat16(vb.z); af.us[6] = *(unsigned short*)&b;
      b = __float2bfloat16(vb.w); af.us[7] = *(unsigned short*)&b;
      const int kb = kc * 32 + kg * 8;
      #pragma unroll
      for (int nt = 0; nt < 8; ++nt) {
        const bfrag bf = *(const bfrag*)&sBT[(nt * 16 + lm) * 136 + kb];
        acc[nt] = __builtin_amdgcn_mfma_f32_16x16x32_bf16(af.v, bf, acc[nt], 0, 0, 0);
      }
    }

    // epilogue h_r: per-head (head = nt>>1) partials, butterfly over the 16-lane row-group
    float ph[4][4];
    #pragma unroll
    for (int hh = 0; hh < 4; ++hh)
      #pragma unroll
      for (int i = 0; i < 4; ++i) ph[hh][i] = 0.f;
    #pragma unroll
    for (int nt = 0; nt < 8; ++nt) {
      const float ar = sAr[nt * 16 + lm];
      #pragma unroll
      for (int i = 0; i < 4; ++i) ph[nt >> 1][i] += acc[nt][i] * ar;
    }
    #pragma unroll
    for (int hh = 0; hh < 4; ++hh)
      #pragma unroll
      for (int i = 0; i < 4; ++i) {
        ph[hh][i] += __shfl_xor(ph[hh][i], 1, 64);
        ph[hh][i] += __shfl_xor(ph[hh][i], 2, 64);
        ph[hh][i] += __shfl_xor(ph[hh][i], 4, 64);
        ph[hh][i] += __shfl_xor(ph[hh][i], 8, 64);
      }
    if (lm == 0) {
      #pragma unroll
      for (int i = 0; i < 4; ++i) {
        const int rr = bid * 64 + w * 16 + kg * 4 + i;
        if (rr < N_TAILN)
          *(float4*)&h_r[(size_t)rr * 4] = make_float4(ph[0][i], ph[1][i], ph[2][i], ph[3][i]);
      }
    }

    // C store (fp16): lane holds D rows kg*4+i, col lm of each 16-col tile
    #pragma unroll
    for (int i = 0; i < 4; ++i) {
      const int rr = bid * 64 + w * 16 + kg * 4 + i;
      if (rr < N_TAILN) {
        __half* orow = out + (size_t)rr * 128 + lm;
        #pragma unroll
        for (int nt = 0; nt < 8; ++nt)
          orow[nt * 16] = __float2half(acc[nt][i]);
      }
    }

  } else if (bid < FB_K2 + FB_P1) {
    // ================= p1 role: partition edges into 196 head-buckets ==================
    int* hist = (int*)smem;
    for (int i = t; i < NB; i += 256) hist[i] = 0;
    __syncthreads();
    const int e0 = (bid - FB_K2) * 1280;               // 1250 blocks x 1280 = 1.6M
    int h[5];
    #pragma unroll
    for (int i = 0; i < 5; ++i) {
      h[i] = head_ind[e0 + i * 256 + t];
      atomicAdd(&hist[h[i] >> 9], 1);
    }
    __syncthreads();
    for (int i = t; i < NB; i += 256) {
      const int c = hist[i];
      hist[i] = (c > 0) ? atomicAdd(&bucketCursor[i], c) : 0;  // hist becomes running cursor
    }
    __syncthreads();
    #pragma unroll
    for (int i = 0; i < 5; ++i) {
      const int e = e0 + i * 256 + t;
      const int hi = h[i];
      const int b = hi >> 9;
      const int pos = atomicAdd(&hist[b], 1);
      recs[b * BCAP + pos] = (unsigned)tail_ind[e] | ((unsigned)etype[e] << 17)
                           | ((unsigned)(hi & 511) << 20);
    }

  } else {
    // ================= k1 role: h_l = head @ wl (16-lane group per node) ===============
    const int gid = (bid - FB_K2 - FB_P1) * 256 + t;   // 6250 blocks -> 100000 nodes
    const int node = gid >> 4, li = gid & 15;
    const float4* row = (const float4*)(feat + (size_t)node * 128 + li * 8);
    const float4 x0 = row[0], x1 = row[1];
    const float* w = wv + li * 32;
    float p0 = 0.f, p1 = 0.f, p2 = 0.f, p3 = 0.f;
    const float xs[8] = {x0.x, x0.y, x0.z, x0.w, x1.x, x1.y, x1.z, x1.w};
    #pragma unroll
    for (int j = 0; j < 8; ++j) {
      const float4 wj = *(const float4*)&w[j * 4];
      p0 += xs[j] * wj.x;
      p1 += xs[j] * wj.y;
      p2 += xs[j] * wj.z;
      p3 += xs[j] * wj.w;
    }
    #pragma unroll
    for (int m = 8; m; m >>= 1) {
      p0 += __shfl_xor(p0, m, 64);
      p1 += __shfl_xor(p1, m, 64);
      p2 += __shfl_xor(p2, m, 64);
      p3 += __shfl_xor(p3, m, 64);
    }
    if (li == 0) *(float4*)(o + (size_t)node * 4) = make_float4(p0, p1, p2, p3);
  }
}

// ---------------- p23: fused {per-head CSR offsets} + {bucket -> CSR scatter} ----------
__global__ __launch_bounds__(1024) void p23(const unsigned int* __restrict__ recs,
                                            const int* __restrict__ bucketCursor,
                                            int* __restrict__ off,
                                            int* __restrict__ pt) {
  __shared__ int cur[HPB];
  __shared__ int red[256];
  const int b = blockIdx.x, t = threadIdx.x;
  if (t < 256) red[t] = (t < b) ? bucketCursor[t] : 0;   // b <= 195 < 256
  if (t < HPB) cur[t] = 0;
  __syncthreads();
  for (int st = 128; st; st >>= 1) {                     // bstart = sum of earlier buckets
    if (t < st) red[t] += red[t + st];
    __syncthreads();
  }
  const int bstart = red[0];
  const int cnt = bucketCursor[b];
  const unsigned int* __restrict__ rb = recs + (size_t)b * BCAP;
  for (int i = t; i < cnt; i += 1024)
    atomicAdd(&cur[rb[i] >> 20], 1);
  __syncthreads();
  const int orig = (t < HPB) ? cur[t] : 0;
  for (int st = 1; st < HPB; st <<= 1) {                 // Hillis-Steele inclusive scan
    int v = 0;
    if (t < HPB && t >= st) v = cur[t - st];
    __syncthreads();
    if (t < HPB) cur[t] += v;
    __syncthreads();
  }
  const int h0 = b * HPB;
  if (t < HPB) {
    const int excl = bstart + cur[t] - orig;             // exclusive prefix
    cur[t] = excl;                                       // becomes scatter cursor
    if (h0 + t < N_HEADN) off[h0 + t] = excl;
  }
  if (b == NB - 1 && t == 0) off[N_HEADN] = NEDGE;
  __syncthreads();
  for (int i = t; i < cnt; i += 1024) {
    const unsigned r = rb[i];
    const int pos = atomicAdd(&cur[r >> 20], 1);
    pt[pos] = (int)(r & 0xFFFFFu);                       // ti | et<<17
  }
}

// ---------------- k4: 16-lane groups, 4 nodes/wave, fp16 gather + v_fma_mix ----------------
// (Round-1 version, measured 79.2 us / VGPR 40 / occ 54%.) NOTE (R3 post-mortem): do NOT
// pin min-waves via __launch_bounds__ — forcing VGPR<=32 spilled (+93MB scratch, 105us).
__global__ __launch_bounds__(256) void k4_agg(const int* __restrict__ off,
                                              const int* __restrict__ pt,
                                              const float* __restrict__ h_l,
                                              const float* __restrict__ h_r,
                                              const float* __restrict__ he,
                                              const __half* __restrict__ h_tail,
                                              float* __restrict__ out) {
  __shared__ __align__(16) float sw[4][4][72];   // [wave][group][li*4+h], stride 72 = conflict-free
  __shared__ int sti[4][4][20];                  // row byte-offsets, stride 20 = conflict-free
  __shared__ __align__(16) float4 she4[8];
  const int wid = threadIdx.x >> 6;
  const int lane = threadIdx.x & 63;
  const int g = lane >> 4, li = lane & 15;
  if (threadIdx.x < 8) she4[threadIdx.x] = ((const float4*)he)[threadIdx.x];
  __syncthreads();                               // only block barrier: she4 visibility
  const int n = blockIdx.x * 16 + wid * 4 + g;   // grid exact: 6250*16
  const int s = off[n], e = off[n + 1];
  const int nch = (e - s + 15) >> 4;
  const float4 hl = *(const float4*)(h_l + (size_t)n * 4);
  const int h = li >> 2;
  const unsigned dby = (unsigned)li * 16u;       // byte offset of lane's 8 dims (fp16)
  float m0 = -1e30f, m1 = -1e30f, m2 = -1e30f, m3 = -1e30f;
  float s0 = 0.f, s1 = 0.f, s2 = 0.f, s3 = 0.f;
  float acc[8];
  #pragma unroll
  for (int d = 0; d < 8; ++d) acc[d] = 0.f;
  float* __restrict__ swg = &sw[wid][g][0];
  int* __restrict__ stig = &sti[wid][g][0];
  const char* __restrict__ htb = (const char*)h_tail;
  for (int c = 0; c < nch; ++c) {
    const int base = s + (c << 4);
    const int rem = min(16, e - base);
    float a0 = -1e30f, a1 = -1e30f, a2 = -1e30f, a3 = -1e30f;
    if (li < rem) {
      const int pk = pt[base + li];
      const unsigned ti = (unsigned)pk & 0x1FFFFu;
      const int et = (pk >> 17) & 7;
      const float4 hr = *(const float4*)((const char*)h_r + (ti << 4));
      const float4 hv = she4[et];
      a0 = hl.x + hr.x + hv.x;
      a1 = hl.y + hr.y + hv.y;
      a2 = hl.z + hr.z + hv.z;
      a3 = hl.w + hr.w + hv.w;
      a0 = fmaxf(a0, SLOPE * a0);                // leaky relu (slope<1)
      a1 = fmaxf(a1, SLOPE * a1);
      a2 = fmaxf(a2, SLOPE * a2);
      a3 = fmaxf(a3, SLOPE * a3);
      stig[li] = (int)(ti << 8);                 // row byte offset (256 B/row)
    }
    float c0 = a0, c1 = a1, c2 = a2, c3 = a3;
    #pragma unroll
    for (int msk = 8; msk; msk >>= 1) {          // width-16 max trees
      c0 = fmaxf(c0, __shfl_xor(c0, msk, 64));
      c1 = fmaxf(c1, __shfl_xor(c1, msk, 64));
      c2 = fmaxf(c2, __shfl_xor(c2, msk, 64));
      c3 = fmaxf(c3, __shfl_xor(c3, msk, 64));
    }
    const float nm0 = fmaxf(m0, c0), nm1 = fmaxf(m1, c1);
    const float nm2 = fmaxf(m2, c2), nm3 = fmaxf(m3, c3);
    const float e0 = __expf(m0 - nm0), e1 = __expf(m1 - nm1);
    const float e2 = __expf(m2 - nm2), e3 = __expf(m3 - nm3);
    const float w0 = __expf(a0 - nm0), w1 = __expf(a1 - nm1);
    const float w2 = __expf(a2 - nm2), w3 = __expf(a3 - nm3);
    float t0 = w0, t1 = w1, t2 = w2, t3 = w3;
    #pragma unroll
    for (int msk = 8; msk; msk >>= 1) {          // width-16 sum trees
      t0 += __shfl_xor(t0, msk, 64);
      t1 += __shfl_xor(t1, msk, 64);
      t2 += __shfl_xor(t2, msk, 64);
      t3 += __shfl_xor(t3, msk, 64);
    }
    s0 = s0 * e0 + t0; s1 = s1 * e1 + t1;
    s2 = s2 * e2 + t2; s3 = s3 * e3 + t3;
    m0 = nm0; m1 = nm1; m2 = nm2; m3 = nm3;
    *(float4*)&swg[li * 4] = make_float4(w0, w1, w2, w3);  // w == 0 for li >= rem
    const float sc = (h == 0) ? e0 : (h == 1) ? e1 : (h == 2) ? e2 : e3;
    #pragma unroll
    for (int d = 0; d < 8; ++d) acc[d] *= sc;
    __builtin_amdgcn_wave_barrier();
    int j = 0;
    for (; j + 4 <= rem; j += 4) {
      const int o0 = stig[j], o1 = stig[j + 1], o2 = stig[j + 2], o3 = stig[j + 3];
      const float q0 = swg[(j + 0) * 4 + h];
      const float q1 = swg[(j + 1) * 4 + h];
      const float q2 = swg[(j + 2) * 4 + h];
      const float q3 = swg[(j + 3) * 4 + h];
      const uint4 v0 = *(const uint4*)(htb + (unsigned)o0 + dby);
      const uint4 v1 = *(const uint4*)(htb + (unsigned)o1 + dby);
      const uint4 v2 = *(const uint4*)(htb + (unsigned)o2 + dby);
      const uint4 v3 = *(const uint4*)(htb + (unsigned)o3 + dby);
      FMA_MIX_LO(acc[0], v0.x, q0); FMA_MIX_HI(acc[1], v0.x, q0);
      FMA_MIX_LO(acc[2], v0.y, q0); FMA_MIX_HI(acc[3], v0.y, q0);
      FMA_MIX_LO(acc[4], v0.z, q0); FMA_MIX_HI(acc[5], v0.z, q0);
      FMA_MIX_LO(acc[6], v0.w, q0); FMA_MIX_HI(acc[7], v0.w, q0);
      FMA_MIX_LO(acc[0], v1.x, q1); FMA_MIX_HI(acc[1], v1.x, q1);
      FMA_MIX_LO(acc[2], v1.y, q1); FMA_MIX_HI(acc[3], v1.y, q1);
      FMA_MIX_LO(acc[4], v1.z, q1); FMA_MIX_HI(acc[5], v1.z, q1);
      FMA_MIX_LO(acc[6], v1.w, q1); FMA_MIX_HI(acc[7], v1.w, q1);
      FMA_MIX_LO(acc[0], v2.x, q2); FMA_MIX_HI(acc[1], v2.x, q2);
      FMA_MIX_LO(acc[2], v2.y, q2); FMA_MIX_HI(acc[3], v2.y, q2);
      FMA_MIX_LO(acc[4], v2.z, q2); FMA_MIX_HI(acc[5], v2.z, q2);
      FMA_MIX_LO(acc[6], v2.w, q2); FMA_MIX_HI(acc[7], v2.w, q2);
      FMA_MIX_LO(acc[0], v3.x, q3); FMA_MIX_HI(acc[1], v3.x, q3);
      FMA_MIX_LO(acc[2], v3.y, q3); FMA_MIX_HI(acc[3], v3.y, q3);
      FMA_MIX_LO(acc[4], v3.z, q3); FMA_MIX_HI(acc[5], v3.z, q3);
      FMA_MIX_LO(acc[6], v3.w, q3); FMA_MIX_HI(acc[7], v3.w, q3);
    }
    for (; j < rem; ++j) {
      const int o = stig[j];
      const float q = swg[j * 4 + h];
      const uint4 v = *(const uint4*)(htb + (unsigned)o + dby);
      FMA_MIX_LO(acc[0], v.x, q); FMA_MIX_HI(acc[1], v.x, q);
      FMA_MIX_LO(acc[2], v.y, q); FMA_MIX_HI(acc[3], v.y, q);
      FMA_MIX_LO(acc[4], v.z, q); FMA_MIX_HI(acc[5], v.z, q);
      FMA_MIX_LO(acc[6], v.w, q); FMA_MIX_HI(acc[7], v.w, q);
    }
    __builtin_amdgcn_wave_barrier();
  }
  const float denom = (h == 0) ? s0 : (h == 1) ? s1 : (h == 2) ? s2 : s3;
  const float inv = denom > 0.f ? 1.f / denom : 0.f;
  float o[8];
  #pragma unroll
  for (int d = 0; d < 8; ++d) {
    const float v = acc[d] * inv;
    o[d] = v > 0.f ? v : expm1f(v);
  }
  float* op = out + (size_t)n * 128 + li * 8;
  *(float4*)op = make_float4(o[0], o[1], o[2], o[3]);
  *(float4*)(op + 4) = make_float4(o[4], o[5], o[6], o[7]);
}

extern "C" void kernel_launch(void* const* d_in, const int* in_sizes, int n_in,
                              void* d_out, int out_size, void* d_ws, size_t ws_size,
                              hipStream_t stream) {
  const float* head = (const float*)d_in[0];
  const float* tail = (const float*)d_in[1];
  const int* elist  = (const int*)d_in[2];
  const int* etype  = (const int*)d_in[3];
  const float* W    = (const float*)d_in[4];
  const float* W_e  = (const float*)d_in[5];
  const float* a_l  = (const float*)d_in[6];
  const float* a_r  = (const float*)d_in[7];
  const float* a_e  = (const float*)d_in[8];
  const float* emb  = (const float*)d_in[9];
  const int* head_ind = elist;
  const int* tail_ind = elist + NEDGE;
  (void)in_sizes; (void)n_in; (void)out_size; (void)ws_size;

  char* p = (char*)d_ws;
  size_t o = 0;
  auto carve = [&](size_t bytes) {
    char* r = p + o;
    o += (bytes + 255) & ~(size_t)255;
    return r;
  };
  // total ~42.6 MB
  __half* h_tail = (__half*)carve((size_t)N_TAILN * 128 * 2);                   // 25.6 MB
  int*   pt     = (int*)   carve((size_t)NEDGE * 4);                            // 6.4 MB
  unsigned int* recs = (unsigned int*)carve((size_t)NB * BCAP * 4);             // 7.2 MB
  float* h_l    = (float*) carve((size_t)N_HEADN * 4 * 4);                      // 1.6 MB
  float* h_r    = (float*) carve((size_t)N_TAILN * 4 * 4);                      // 1.6 MB
  int*   off    = (int*)   carve((size_t)(N_HEADN + 1) * 4);                    // 0.4 MB
  int*   bucketCursor = (int*)carve(NB * 4);
  float* wl     = (float*) carve(128 * 4 * 4);
  float* he     = (float*) carve(8 * 4 * 4);
  __hip_bfloat16* WbT = (__hip_bfloat16*)carve(16384 * 2);                      // 32 KB

  hipMemsetAsync(bucketCursor, 0, NB * sizeof(int), stream);
  k0m<<<16, 256, 0, stream>>>(W, W_e, a_l, a_e, emb, WbT, wl, he);
  fusedA<<<FB_K2 + FB_P1 + FB_K1, 256, 0, stream>>>(
      tail, WbT, a_r, h_tail, h_r,
      head_ind, tail_ind, etype, bucketCursor, recs,
      head, wl, h_l);
  p23<<<NB, 1024, 0, stream>>>(recs, bucketCursor, off, pt);
  k4_agg<<<N_HEADN / 16, 256, 0, stream>>>(off, pt, h_l, h_r, he, h_tail, (float*)d_out);
}

// Round 13
// 298.978 us; speedup vs baseline: 1.2187x; 1.0159x over previous
//
#include <hip/hip_runtime.h>
#include <hip/hip_bf16.h>
#include <hip/hip_fp16.h>
#include <math.h>

#define N_HEADN 100000
#define N_TAILN 100000
#define NEDGE   1600000
#define SLOPE   0.2f

#define NB   196      // buckets: head>>9
#define HPB  512      // heads per bucket
#define BCAP 9216     // bucket capacity (mean 8191, sigma ~90; 9216 = +11 sigma)

// fusedA role ranges
#define FB_K2 1563    // k2 role: 1563 blocks x 64 rows
#define FB_P1 1250    // p1 role: 1250 blocks x 1280 edges
#define FB_K1 6250    // k1 role: 6250 blocks x 16 nodes

static __device__ __forceinline__ float bf2f(__hip_bfloat16 x) { return __bfloat162float(x); }

// f16 source (lo/hi half of packed u32), fp32 multiplier + fp32 accumulate, 1 instr/dim
#define FMA_MIX_LO(acc, pk, q) \
  asm("v_fma_mix_f32 %0, %1, %2, %0 op_sel_hi:[1,0,0]" : "+v"(acc) : "v"(pk), "v"(q))
#define FMA_MIX_HI(acc, pk, q) \
  asm("v_fma_mix_f32 %0, %1, %2, %0 op_sel:[1,0,0] op_sel_hi:[1,0,0]" : "+v"(acc) : "v"(pk), "v"(q))

typedef __attribute__((ext_vector_type(8))) short bfrag;   // 8 bf16 (4 VGPRs)
typedef __attribute__((ext_vector_type(4))) float ffrag;   // 4 fp32 acc

// ---------------- k0m: { W -> bf16 TRANSPOSED } + { wl[128][4], he[8][4] prep } ----------
__global__ __launch_bounds__(256) void k0m(const float* __restrict__ W,
                                           const float* __restrict__ W_e,
                                           const float* __restrict__ a_l,
                                           const float* __restrict__ a_e,
                                           const float* __restrict__ emb,
                                           __hip_bfloat16* __restrict__ WbT,
                                           float* __restrict__ wl,
                                           float* __restrict__ he) {
  const int i = (blockIdx.x * 256 + threadIdx.x) * 4;   // 4 consecutive W elems (same row)
  const int r = i >> 7, c = i & 127;
  const float4 v = *(const float4*)&W[i];
  WbT[(size_t)(c + 0) * 128 + r] = __float2bfloat16(v.x);
  WbT[(size_t)(c + 1) * 128 + r] = __float2bfloat16(v.y);
  WbT[(size_t)(c + 2) * 128 + r] = __float2bfloat16(v.z);
  WbT[(size_t)(c + 3) * 128 + r] = __float2bfloat16(v.w);
  if (blockIdx.x == 0 && threadIdx.x < 128) {
    const int t = threadIdx.x;
    #pragma unroll
    for (int h = 0; h < 4; ++h) {
      float sl = 0.f;
      for (int d = 0; d < 32; ++d)
        sl += W[t * 128 + h * 32 + d] * a_l[h * 32 + d];
      wl[t * 4 + h] = sl;
    }
    if (t < 32) {
      const int et = t >> 2, h = t & 3;
      float acc = 0.f;
      for (int d = 0; d < 32; ++d) {
        float tmp = 0.f;
        for (int f = 0; f < 32; ++f)
          tmp += emb[et * 32 + f] * W_e[f * 128 + h * 32 + d];
        acc += a_e[h * 32 + d] * tmp;
      }
      he[et * 4 + h] = acc;
    }
  }
}

// ---------------- fusedA: role-switched { k2-MFMA | p1-partition | k1-h_l } -------------
__global__ __launch_bounds__(256) void fusedA(
    const float* __restrict__ A,            // tail features (k2)
    const __hip_bfloat16* __restrict__ WbT,
    const float* __restrict__ a_r,
    __half* __restrict__ out,               // h_tail fp16
    float* __restrict__ h_r,
    const int* __restrict__ head_ind,       // p1
    const int* __restrict__ tail_ind,
    const int* __restrict__ etype,
    int* __restrict__ bucketCursor,
    unsigned int* __restrict__ recs,
    const float* __restrict__ feat,         // head features (k1)
    const float* __restrict__ wv,           // wl
    float* __restrict__ o) {                // h_l
  __shared__ __align__(16) char smem[128 * 136 * 2 + 512];
  const int bid = blockIdx.x;
  const int t = threadIdx.x;

  if (bid < FB_K2) {
    // ================= k2 role: h_tail = tail @ W via MFMA + h_r epilogue ==============
    __hip_bfloat16* sBT = (__hip_bfloat16*)smem;       // [c][k], stride 136
    float* sAr = (float*)(smem + 128 * 136 * 2);
    {
      const uint4* src = (const uint4*)WbT;            // contiguous in k
      #pragma unroll
      for (int it = 0; it < 8; ++it) {
        const int i = it * 256 + t;                    // chunk i: c = i>>4, k0 = (i&15)*8
        *(uint4*)&sBT[(i >> 4) * 136 + (i & 15) * 8] = src[i];
      }
    }
    if (t < 128) sAr[t] = a_r[t];
    __syncthreads();

    const int w = t >> 6, l = t & 63;
    const int lm = l & 15, kg = l >> 4;
    const int row = bid * 64 + w * 16 + lm;
    const int rowc = row < N_TAILN ? row : N_TAILN - 1;
    const float* __restrict__ Arow = A + (size_t)rowc * 128 + kg * 8;

    ffrag acc[8];
    #pragma unroll
    for (int nt = 0; nt < 8; ++nt) acc[nt] = (ffrag){0.f, 0.f, 0.f, 0.f};

    #pragma unroll
    for (int kc = 0; kc < 4; ++kc) {
      const float4 va = *(const float4*)(Arow + kc * 32);
      const float4 vb = *(const float4*)(Arow + kc * 32 + 4);
      union { unsigned short us[8]; bfrag v; } af;
      __hip_bfloat16 b;
      b = __float2bfloat16(va.x); af.us[0] = *(unsigned short*)&b;
      b = __float2bfloat16(va.y); af.us[1] = *(unsigned short*)&b;
      b = __float2bfloat16(va.z); af.us[2] = *(unsigned short*)&b;
      b = __float2bfloat16(va.w); af.us[3] = *(unsigned short*)&b;
      b = __float2bfloat16(vb.x); af.us[4] = *(unsigned short*)&b;
      b = __float2bfloat16(vb.y); af.us[5] = *(unsigned short*)&b;
      b = __float2bfloat16(vb.z); af.us[6] = *(unsigned short*)&b;
      b = __float2bfloat16(vb.w); af.us[7] = *(unsigned short*)&b;
      const int kb = kc * 32 + kg * 8;
      #pragma unroll
      for (int nt = 0; nt < 8; ++nt) {
        const bfrag bf = *(const bfrag*)&sBT[(nt * 16 + lm) * 136 + kb];
        acc[nt] = __builtin_amdgcn_mfma_f32_16x16x32_bf16(af.v, bf, acc[nt], 0, 0, 0);
      }
    }

    // epilogue h_r: per-head (head = nt>>1) partials, butterfly over the 16-lane row-group
    float ph[4][4];
    #pragma unroll
    for (int hh = 0; hh < 4; ++hh)
      #pragma unroll
      for (int i = 0; i < 4; ++i) ph[hh][i] = 0.f;
    #pragma unroll
    for (int nt = 0; nt < 8; ++nt) {
      const float ar = sAr[nt * 16 + lm];
      #pragma unroll
      for (int i = 0; i < 4; ++i) ph[nt >> 1][i] += acc[nt][i] * ar;
    }
    #pragma unroll
    for (int hh = 0; hh < 4; ++hh)
      #pragma unroll
      for (int i = 0; i < 4; ++i) {
        ph[hh][i] += __shfl_xor(ph[hh][i], 1, 64);
        ph[hh][i] += __shfl_xor(ph[hh][i], 2, 64);
        ph[hh][i] += __shfl_xor(ph[hh][i], 4, 64);
        ph[hh][i] += __shfl_xor(ph[hh][i], 8, 64);
      }
    if (lm == 0) {
      #pragma unroll
      for (int i = 0; i < 4; ++i) {
        const int rr = bid * 64 + w * 16 + kg * 4 + i;
        if (rr < N_TAILN)
          *(float4*)&h_r[(size_t)rr * 4] = make_float4(ph[0][i], ph[1][i], ph[2][i], ph[3][i]);
      }
    }

    // C store (fp16): lane holds D rows kg*4+i, col lm of each 16-col tile
    #pragma unroll
    for (int i = 0; i < 4; ++i) {
      const int rr = bid * 64 + w * 16 + kg * 4 + i;
      if (rr < N_TAILN) {
        __half* orow = out + (size_t)rr * 128 + lm;
        #pragma unroll
        for (int nt = 0; nt < 8; ++nt)
          orow[nt * 16] = __float2half(acc[nt][i]);
      }
    }

  } else if (bid < FB_K2 + FB_P1) {
    // ================= p1 role: partition edges into 196 head-buckets ==================
    int* hist = (int*)smem;
    for (int i = t; i < NB; i += 256) hist[i] = 0;
    __syncthreads();
    const int e0 = (bid - FB_K2) * 1280;               // 1250 blocks x 1280 = 1.6M
    int h[5];
    #pragma unroll
    for (int i = 0; i < 5; ++i) {
      h[i] = head_ind[e0 + i * 256 + t];
      atomicAdd(&hist[h[i] >> 9], 1);
    }
    __syncthreads();
    for (int i = t; i < NB; i += 256) {
      const int c = hist[i];
      hist[i] = (c > 0) ? atomicAdd(&bucketCursor[i], c) : 0;  // hist becomes running cursor
    }
    __syncthreads();
    #pragma unroll
    for (int i = 0; i < 5; ++i) {
      const int e = e0 + i * 256 + t;
      const int hi = h[i];
      const int b = hi >> 9;
      const int pos = atomicAdd(&hist[b], 1);
      recs[b * BCAP + pos] = (unsigned)tail_ind[e] | ((unsigned)etype[e] << 17)
                           | ((unsigned)(hi & 511) << 20);
    }

  } else {
    // ================= k1 role: h_l = head @ wl (16-lane group per node) ===============
    const int gid = (bid - FB_K2 - FB_P1) * 256 + t;   // 6250 blocks -> 100000 nodes
    const int node = gid >> 4, li = gid & 15;
    const float4* row = (const float4*)(feat + (size_t)node * 128 + li * 8);
    const float4 x0 = row[0], x1 = row[1];
    const float* w = wv + li * 32;
    float p0 = 0.f, p1 = 0.f, p2 = 0.f, p3 = 0.f;
    const float xs[8] = {x0.x, x0.y, x0.z, x0.w, x1.x, x1.y, x1.z, x1.w};
    #pragma unroll
    for (int j = 0; j < 8; ++j) {
      const float4 wj = *(const float4*)&w[j * 4];
      p0 += xs[j] * wj.x;
      p1 += xs[j] * wj.y;
      p2 += xs[j] * wj.z;
      p3 += xs[j] * wj.w;
    }
    #pragma unroll
    for (int m = 8; m; m >>= 1) {
      p0 += __shfl_xor(p0, m, 64);
      p1 += __shfl_xor(p1, m, 64);
      p2 += __shfl_xor(p2, m, 64);
      p3 += __shfl_xor(p3, m, 64);
    }
    if (li == 0) *(float4*)(o + (size_t)node * 4) = make_float4(p0, p1, p2, p3);
  }
}

// ---------------- p23: fused {per-head CSR offsets} + {bucket -> CSR scatter} ----------
__global__ __launch_bounds__(1024) void p23(const unsigned int* __restrict__ recs,
                                            const int* __restrict__ bucketCursor,
                                            int* __restrict__ off,
                                            int* __restrict__ pt) {
  __shared__ int cur[HPB];
  __shared__ int red[256];
  const int b = blockIdx.x, t = threadIdx.x;
  if (t < 256) red[t] = (t < b) ? bucketCursor[t] : 0;   // b <= 195 < 256
  if (t < HPB) cur[t] = 0;
  __syncthreads();
  for (int st = 128; st; st >>= 1) {                     // bstart = sum of earlier buckets
    if (t < st) red[t] += red[t + st];
    __syncthreads();
  }
  const int bstart = red[0];
  const int cnt = bucketCursor[b];
  const unsigned int* __restrict__ rb = recs + (size_t)b * BCAP;
  for (int i = t; i < cnt; i += 1024)
    atomicAdd(&cur[rb[i] >> 20], 1);
  __syncthreads();
  const int orig = (t < HPB) ? cur[t] : 0;
  for (int st = 1; st < HPB; st <<= 1) {                 // Hillis-Steele inclusive scan
    int v = 0;
    if (t < HPB && t >= st) v = cur[t - st];
    __syncthreads();
    if (t < HPB) cur[t] += v;
    __syncthreads();
  }
  const int h0 = b * HPB;
  if (t < HPB) {
    const int excl = bstart + cur[t] - orig;             // exclusive prefix
    cur[t] = excl;                                       // becomes scatter cursor
    if (h0 + t < N_HEADN) off[h0 + t] = excl;
  }
  if (b == NB - 1 && t == 0) off[N_HEADN] = NEDGE;
  __syncthreads();
  for (int i = t; i < cnt; i += 1024) {
    const unsigned r = rb[i];
    const int pos = atomicAdd(&cur[r >> 20], 1);
    pt[pos] = (int)(r & 0xFFFFFu);                       // ti | et<<17
  }
}

// ---------------- k4: 16-lane groups, CHUNK=32 (2 edges/lane), fp16 + v_fma_mix --------
// R3's CHUNK=32 body (harness-verified correct in R4) WITHOUT the launch-bounds pin that
// caused its spill (VGPR forced 32 -> 93MB scratch). One chunk covers 32 edges so
// P(deg<=32) ~ 99.98% -> nearly every wave runs exactly ONE chunk iteration (vs E[max
// over 4 groups of ceil(deg/16)] ~ 1.9 at CHUNK=16), halving per-chunk fixed cost.
// Spill check: WRITE_SIZE must stay ~50MB. VGPR must stay <= 64 (else occ halves: revert).
__global__ __launch_bounds__(256) void k4_agg(const int* __restrict__ off,
                                              const int* __restrict__ pt,
                                              const float* __restrict__ h_l,
                                              const float* __restrict__ h_r,
                                              const float* __restrict__ he,
                                              const __half* __restrict__ h_tail,
                                              float* __restrict__ out) {
  __shared__ __align__(16) float sw[4][4][136];  // 32 slots x4 + pad; group stride 136
  __shared__ int sti[4][4][36];                  // 32 row byte-offsets + pad
  __shared__ __align__(16) float4 she4[8];
  const int wid = threadIdx.x >> 6;
  const int lane = threadIdx.x & 63;
  const int g = lane >> 4, li = lane & 15;
  if (threadIdx.x < 8) she4[threadIdx.x] = ((const float4*)he)[threadIdx.x];
  __syncthreads();                               // only block barrier: she4 visibility
  const int n = blockIdx.x * 16 + wid * 4 + g;   // grid exact: 6250*16
  const int s = off[n], e = off[n + 1];
  const int nch = (e - s + 31) >> 5;
  const float4 hl = *(const float4*)(h_l + (size_t)n * 4);
  const int h = li >> 2;
  const unsigned dby = (unsigned)li * 16u;       // byte offset of lane's 8 dims (fp16)
  float m0 = -1e30f, m1 = -1e30f, m2 = -1e30f, m3 = -1e30f;
  float s0 = 0.f, s1 = 0.f, s2 = 0.f, s3 = 0.f;
  float acc[8];
  #pragma unroll
  for (int d = 0; d < 8; ++d) acc[d] = 0.f;
  float* __restrict__ swg = &sw[wid][g][0];
  int* __restrict__ stig = &sti[wid][g][0];
  const char* __restrict__ htb = (const char*)h_tail;
  for (int c = 0; c < nch; ++c) {
    const int base = s + (c << 5);
    const int rem = min(32, e - base);
    // edge A = base+li, edge B = base+16+li
    float a0 = -1e30f, a1 = -1e30f, a2 = -1e30f, a3 = -1e30f;
    float b0 = -1e30f, b1 = -1e30f, b2 = -1e30f, b3 = -1e30f;
    if (li < rem) {
      const int pk = pt[base + li];
      const unsigned ti = (unsigned)pk & 0x1FFFFu;
      const float4 hr = *(const float4*)((const char*)h_r + (ti << 4));
      const float4 hv = she4[(pk >> 17) & 7];
      a0 = hl.x + hr.x + hv.x;
      a1 = hl.y + hr.y + hv.y;
      a2 = hl.z + hr.z + hv.z;
      a3 = hl.w + hr.w + hv.w;
      a0 = fmaxf(a0, SLOPE * a0);                // leaky relu (slope<1)
      a1 = fmaxf(a1, SLOPE * a1);
      a2 = fmaxf(a2, SLOPE * a2);
      a3 = fmaxf(a3, SLOPE * a3);
      stig[li] = (int)(ti << 8);                 // h_tail row byte offset (256 B/row)
    }
    if (li + 16 < rem) {
      const int pk = pt[base + 16 + li];
      const unsigned ti = (unsigned)pk & 0x1FFFFu;
      const float4 hr = *(const float4*)((const char*)h_r + (ti << 4));
      const float4 hv = she4[(pk >> 17) & 7];
      b0 = hl.x + hr.x + hv.x;
      b1 = hl.y + hr.y + hv.y;
      b2 = hl.z + hr.z + hv.z;
      b3 = hl.w + hr.w + hv.w;
      b0 = fmaxf(b0, SLOPE * b0);
      b1 = fmaxf(b1, SLOPE * b1);
      b2 = fmaxf(b2, SLOPE * b2);
      b3 = fmaxf(b3, SLOPE * b3);
      stig[li + 16] = (int)(ti << 8);
    }
    float c0 = fmaxf(a0, b0), c1 = fmaxf(a1, b1);
    float c2 = fmaxf(a2, b2), c3 = fmaxf(a3, b3);
    #pragma unroll
    for (int msk = 8; msk; msk >>= 1) {          // width-16 max trees (32 edges)
      c0 = fmaxf(c0, __shfl_xor(c0, msk, 64));
      c1 = fmaxf(c1, __shfl_xor(c1, msk, 64));
      c2 = fmaxf(c2, __shfl_xor(c2, msk, 64));
      c3 = fmaxf(c3, __shfl_xor(c3, msk, 64));
    }
    const float nm0 = fmaxf(m0, c0), nm1 = fmaxf(m1, c1);
    const float nm2 = fmaxf(m2, c2), nm3 = fmaxf(m3, c3);
    const float e0 = __expf(m0 - nm0), e1 = __expf(m1 - nm1);
    const float e2 = __expf(m2 - nm2), e3 = __expf(m3 - nm3);
    const float wa0 = __expf(a0 - nm0), wa1 = __expf(a1 - nm1);
    const float wa2 = __expf(a2 - nm2), wa3 = __expf(a3 - nm3);
    const float wb0 = __expf(b0 - nm0), wb1 = __expf(b1 - nm1);
    const float wb2 = __expf(b2 - nm2), wb3 = __expf(b3 - nm3);
    float t0 = wa0 + wb0, t1 = wa1 + wb1;
    float t2 = wa2 + wb2, t3 = wa3 + wb3;
    #pragma unroll
    for (int msk = 8; msk; msk >>= 1) {          // width-16 sum trees (32 edges)
      t0 += __shfl_xor(t0, msk, 64);
      t1 += __shfl_xor(t1, msk, 64);
      t2 += __shfl_xor(t2, msk, 64);
      t3 += __shfl_xor(t3, msk, 64);
    }
    s0 = s0 * e0 + t0; s1 = s1 * e1 + t1;
    s2 = s2 * e2 + t2; s3 = s3 * e3 + t3;
    m0 = nm0; m1 = nm1; m2 = nm2; m3 = nm3;
    *(float4*)&swg[li * 4] = make_float4(wa0, wa1, wa2, wa3);        // 0 for li >= rem
    *(float4*)&swg[(li + 16) * 4] = make_float4(wb0, wb1, wb2, wb3); // 0 for li+16 >= rem
    const float sc = (h == 0) ? e0 : (h == 1) ? e1 : (h == 2) ? e2 : e3;
    #pragma unroll
    for (int d = 0; d < 8; ++d) acc[d] *= sc;
    __builtin_amdgcn_wave_barrier();
    int j = 0;
    for (; j + 4 <= rem; j += 4) {
      const int o0 = stig[j], o1 = stig[j + 1], o2 = stig[j + 2], o3 = stig[j + 3];
      const float q0 = swg[(j + 0) * 4 + h];
      const float q1 = swg[(j + 1) * 4 + h];
      const float q2 = swg[(j + 2) * 4 + h];
      const float q3 = swg[(j + 3) * 4 + h];
      const uint4 v0 = *(const uint4*)(htb + (unsigned)o0 + dby);
      const uint4 v1 = *(const uint4*)(htb + (unsigned)o1 + dby);
      const uint4 v2 = *(const uint4*)(htb + (unsigned)o2 + dby);
      const uint4 v3 = *(const uint4*)(htb + (unsigned)o3 + dby);
      FMA_MIX_LO(acc[0], v0.x, q0); FMA_MIX_HI(acc[1], v0.x, q0);
      FMA_MIX_LO(acc[2], v0.y, q0); FMA_MIX_HI(acc[3], v0.y, q0);
      FMA_MIX_LO(acc[4], v0.z, q0); FMA_MIX_HI(acc[5], v0.z, q0);
      FMA_MIX_LO(acc[6], v0.w, q0); FMA_MIX_HI(acc[7], v0.w, q0);
      FMA_MIX_LO(acc[0], v1.x, q1); FMA_MIX_HI(acc[1], v1.x, q1);
      FMA_MIX_LO(acc[2], v1.y, q1); FMA_MIX_HI(acc[3], v1.y, q1);
      FMA_MIX_LO(acc[4], v1.z, q1); FMA_MIX_HI(acc[5], v1.z, q1);
      FMA_MIX_LO(acc[6], v1.w, q1); FMA_MIX_HI(acc[7], v1.w, q1);
      FMA_MIX_LO(acc[0], v2.x, q2); FMA_MIX_HI(acc[1], v2.x, q2);
      FMA_MIX_LO(acc[2], v2.y, q2); FMA_MIX_HI(acc[3], v2.y, q2);
      FMA_MIX_LO(acc[4], v2.z, q2); FMA_MIX_HI(acc[5], v2.z, q2);
      FMA_MIX_LO(acc[6], v2.w, q2); FMA_MIX_HI(acc[7], v2.w, q2);
      FMA_MIX_LO(acc[0], v3.x, q3); FMA_MIX_HI(acc[1], v3.x, q3);
      FMA_MIX_LO(acc[2], v3.y, q3); FMA_MIX_HI(acc[3], v3.y, q3);
      FMA_MIX_LO(acc[4], v3.z, q3); FMA_MIX_HI(acc[5], v3.z, q3);
      FMA_MIX_LO(acc[6], v3.w, q3); FMA_MIX_HI(acc[7], v3.w, q3);
    }
    for (; j < rem; ++j) {
      const int o = stig[j];
      const float q = swg[j * 4 + h];
      const uint4 v = *(const uint4*)(htb + (unsigned)o + dby);
      FMA_MIX_LO(acc[0], v.x, q); FMA_MIX_HI(acc[1], v.x, q);
      FMA_MIX_LO(acc[2], v.y, q); FMA_MIX_HI(acc[3], v.y, q);
      FMA_MIX_LO(acc[4], v.z, q); FMA_MIX_HI(acc[5], v.z, q);
      FMA_MIX_LO(acc[6], v.w, q); FMA_MIX_HI(acc[7], v.w, q);
    }
    __builtin_amdgcn_wave_barrier();
  }
  const float denom = (h == 0) ? s0 : (h == 1) ? s1 : (h == 2) ? s2 : s3;
  const float inv = denom > 0.f ? 1.f / denom : 0.f;
  float o[8];
  #pragma unroll
  for (int d = 0; d < 8; ++d) {
    const float v = acc[d] * inv;
    o[d] = v > 0.f ? v : expm1f(v);
  }
  float* op = out + (size_t)n * 128 + li * 8;
  *(float4*)op = make_float4(o[0], o[1], o[2], o[3]);
  *(float4*)(op + 4) = make_float4(o[4], o[5], o[6], o[7]);
}

extern "C" void kernel_launch(void* const* d_in, const int* in_sizes, int n_in,
                              void* d_out, int out_size, void* d_ws, size_t ws_size,
                              hipStream_t stream) {
  const float* head = (const float*)d_in[0];
  const float* tail = (const float*)d_in[1];
  const int* elist  = (const int*)d_in[2];
  const int* etype  = (const int*)d_in[3];
  const float* W    = (const float*)d_in[4];
  const float* W_e  = (const float*)d_in[5];
  const float* a_l  = (const float*)d_in[6];
  const float* a_r  = (const float*)d_in[7];
  const float* a_e  = (const float*)d_in[8];
  const float* emb  = (const float*)d_in[9];
  const int* head_ind = elist;
  const int* tail_ind = elist + NEDGE;
  (void)in_sizes; (void)n_in; (void)out_size; (void)ws_size;

  char* p = (char*)d_ws;
  size_t o = 0;
  auto carve = [&](size_t bytes) {
    char* r = p + o;
    o += (bytes + 255) & ~(size_t)255;
    return r;
  };
  // total ~42.6 MB
  __half* h_tail = (__half*)carve((size_t)N_TAILN * 128 * 2);                   // 25.6 MB
  int*   pt     = (int*)   carve((size_t)NEDGE * 4);                            // 6.4 MB
  unsigned int* recs = (unsigned int*)carve((size_t)NB * BCAP * 4);             // 7.2 MB
  float* h_l    = (float*) carve((size_t)N_HEADN * 4 * 4);                      // 1.6 MB
  float* h_r    = (float*) carve((size_t)N_TAILN * 4 * 4);                      // 1.6 MB
  int*   off    = (int*)   carve((size_t)(N_HEADN + 1) * 4);                    // 0.4 MB
  int*   bucketCursor = (int*)carve(NB * 4);
  float* wl     = (float*) carve(128 * 4 * 4);
  float* he     = (float*) carve(8 * 4 * 4);
  __hip_bfloat16* WbT = (__hip_bfloat16*)carve(16384 * 2);                      // 32 KB

  hipMemsetAsync(bucketCursor, 0, NB * sizeof(int), stream);
  k0m<<<16, 256, 0, stream>>>(W, W_e, a_l, a_e, emb, WbT, wl, he);
  fusedA<<<FB_K2 + FB_P1 + FB_K1, 256, 0, stream>>>(
      tail, WbT, a_r, h_tail, h_r,
      head_ind, tail_ind, etype, bucketCursor, recs,
      head, wl, h_l);
  p23<<<NB, 1024, 0, stream>>>(recs, bucketCursor, off, pt);
  k4_agg<<<N_HEADN / 16, 256, 0, stream>>>(off, pt, h_l, h_r, he, h_tail, (float*)d_out);
}